// Round 7
// baseline (904.250 us; speedup 1.0000x reference)
//
#include <hip/hip_runtime.h>
#include <math.h>

#define NN 8192
#define NE 262144
#define FIN 128
#define HC 256
#define CC 64
#define NCLS 8
#define NDNT 16   // nodes per block in k_node
#define ABNT 16   // nodes per block in k_AB
#define G1NT 16   // nodes per block in k_gcn1

// ---------------- ws layout (floats) ----------------
constexpr size_t OFF_XS    = 0;                              // N*256
constexpr size_t OFF_ASRC  = OFF_XS + (size_t)NN * 256;      // N*4
constexpr size_t OFF_ADST  = OFF_ASRC + (size_t)NN * 4;      // N*4
constexpr size_t OFF_ALPHA = OFF_ADST + (size_t)NN * 4;      // E*4
constexpr size_t OFF_CONF1 = OFF_ALPHA + (size_t)NE * 4;     // E
constexpr size_t OFF_CONF2 = OFF_CONF1 + (size_t)NE;         // E
constexpr size_t OFF_COEF1 = OFF_CONF2 + (size_t)NE;         // E
constexpr size_t OFF_COEF2 = OFF_COEF1 + (size_t)NE;         // E
constexpr size_t OFF_H1    = OFF_COEF2 + (size_t)NE;         // N*256
constexpr size_t OFF_A     = OFF_H1 + (size_t)NN * 256;      // N*256
constexpr size_t OFF_B     = OFF_A + (size_t)NN * 256;       // N*256
constexpr size_t OFF_H2    = OFF_B + (size_t)NN * 256;       // N*64
constexpr size_t OFF_DINV  = OFF_H2 + (size_t)NN * 64;       // N
constexpr size_t OFF_SUMEA = OFF_DINV + (size_t)NN;          // 4 (3 used)
constexpr size_t OFF_M     = OFF_SUMEA + 4;                  // 12
constexpr size_t OFF_AELOOP= OFF_M + 12;                     // 4
constexpr size_t OFF_INT   = OFF_AELOOP + 4;                 // ints from here
constexpr size_t IOFF_DEGC    = 0;                    // NN
constexpr size_t IOFF_DEGR    = IOFF_DEGC + NN;       // NN
constexpr size_t IOFF_COLOFF  = IOFF_DEGR + NN;       // NN+1
constexpr size_t IOFF_CURC    = IOFF_COLOFF + NN + 1; // NN
constexpr size_t IOFF_ROWOFF  = IOFF_CURC + NN;       // NN+1
constexpr size_t IOFF_CURR    = IOFF_ROWOFF + NN + 1; // NN
constexpr size_t IOFF_CSR_ROW = IOFF_CURR + NN;       // NE (col-CSR: src row per slot)
constexpr size_t IOFF_CSR_EID = IOFF_CSR_ROW + NE;    // NE
constexpr size_t IOFF_CSRR_COL= IOFF_CSR_EID + NE;    // NE (row-CSR: dst col per slot)
constexpr size_t IOFF_CSRR_EID= IOFF_CSRR_COL + NE;   // NE

// ---------------- helpers ----------------
__device__ __forceinline__ float wave_sum(float v) {
    for (int o = 32; o; o >>= 1) v += __shfl_xor(v, o);
    return v;
}
__device__ __forceinline__ float wave_max(float v) {
    for (int o = 32; o; o >>= 1) v = fmaxf(v, __shfl_xor(v, o));
    return v;
}
__device__ __forceinline__ float eluf(float v) { return v > 0.f ? v : (expf(v) - 1.f); }
__device__ __forceinline__ float sigmf(float v) { return 1.f / (1.f + expf(-v)); }

// ---------------- kernels ----------------
// zero counters, set adj diag (after memset in stream order), compute M[3][4]
__global__ __launch_bounds__(256) void k_init(int* deg_col, int* deg_row, float* sum_ea,
                                              float* adj, const float* lew,
                                              const float* att_edge, float* M) {
    int i = blockIdx.x * blockDim.x + threadIdx.x;
    deg_col[i] = 0;
    deg_row[i] = 0;
    adj[(size_t)i * NN + i] = 1.f;
    if (i < 3) sum_ea[i] = 0.f;
    if (i < 12) {
        int d = i >> 2, h = i & 3;
        float s = 0.f;
        for (int c = 0; c < 64; c++) s = fmaf(lew[d * 256 + h * 64 + c], att_edge[h * 64 + c], s);
        M[i] = s; // M[d*4+h]
    }
}

// xs = x @ gat_lin_w ; a_src/a_dst per (node, head). Tiled: NDNT nodes/block.
__global__ __launch_bounds__(256) void k_node(const float* __restrict__ x, const float* __restrict__ W,
                                              const float* __restrict__ att_src, const float* __restrict__ att_dst,
                                              float* __restrict__ xs, float* __restrict__ a_src, float* __restrict__ a_dst) {
    __shared__ float xl[NDNT * FIN];
    int b = blockIdx.x, t = threadIdx.x;
    size_t base = (size_t)b * NDNT;
#pragma unroll
    for (int q = 0; q < NDNT * FIN / 256; ++q) {
        int idx = q * 256 + t;
        xl[idx] = x[base * FIN + idx];
    }
    __syncthreads();
    float acc[NDNT];
#pragma unroll
    for (int n = 0; n < NDNT; ++n) acc[n] = 0.f;
    for (int k = 0; k < FIN; ++k) {
        float wv = W[k * 256 + t];
#pragma unroll
        for (int n = 0; n < NDNT; ++n) acc[n] = fmaf(xl[n * FIN + k], wv, acc[n]);
    }
    float as = att_src[t], ad = att_dst[t];
#pragma unroll
    for (int n = 0; n < NDNT; ++n) {
        xs[(base + n) * 256 + t] = acc[n];
        float ps = wave_sum(acc[n] * as);
        float pd = wave_sum(acc[n] * ad);
        if ((t & 63) == 0) {
            a_src[(base + n) * 4 + (t >> 6)] = ps;
            a_dst[(base + n) * 4 + (t >> 6)] = pd;
        }
    }
}

__global__ __launch_bounds__(256) void k_edge(const int* __restrict__ ei, const float* __restrict__ eattr,
                                              const float* __restrict__ M,
                                              const float* __restrict__ a_src, const float* __restrict__ a_dst,
                                              const float* __restrict__ c1w, const float* __restrict__ c1b,
                                              const float* __restrict__ c2w, const float* __restrict__ c2b,
                                              float* __restrict__ alpha, float* __restrict__ conf1, float* __restrict__ conf2,
                                              int* __restrict__ deg_col, int* __restrict__ deg_row, float* __restrict__ sum_ea) {
    int e = blockIdx.x * 256 + threadIdx.x;
    int r = ei[e], c = ei[NE + e];
    float ea0 = eattr[e * 3 + 0], ea1 = eattr[e * 3 + 1], ea2 = eattr[e * 3 + 2];
#pragma unroll
    for (int h = 0; h < 4; h++) {
        float ae = fmaf(ea0, M[0 * 4 + h], fmaf(ea1, M[1 * 4 + h], ea2 * M[2 * 4 + h]));
        float v = a_src[r * 4 + h] + a_dst[c * 4 + h] + ae;
        alpha[(size_t)e * 4 + h] = v > 0.f ? v : 0.2f * v;
    }
    conf1[e] = sigmf(fmaf(ea0, c1w[0], fmaf(ea1, c1w[1], fmaf(ea2, c1w[2], c1b[0]))));
    conf2[e] = sigmf(fmaf(ea0, c2w[0], fmaf(ea1, c2w[1], fmaf(ea2, c2w[2], c2b[0]))));
    atomicAdd(&deg_col[c], 1);
    atomicAdd(&deg_row[r], 1);
    float s0 = wave_sum(ea0), s1 = wave_sum(ea1), s2 = wave_sum(ea2);
    if ((threadIdx.x & 63) == 0) {
        atomicAdd(&sum_ea[0], s0); atomicAdd(&sum_ea[1], s1); atomicAdd(&sum_ea[2], s2);
    }
}

// self-loop logit constant + dinv
__global__ __launch_bounds__(256) void k_loopdinv(const float* sum_ea, const float* M, float* aeloop,
                                                  const int* deg_row, float* dinv) {
    int i = blockIdx.x * blockDim.x + threadIdx.x;
    if (i < 4) {
        float m0 = sum_ea[0] * (1.f / NE), m1 = sum_ea[1] * (1.f / NE), m2 = sum_ea[2] * (1.f / NE);
        aeloop[i] = fmaf(m0, M[0 * 4 + i], fmaf(m1, M[1 * 4 + i], m2 * M[2 * 4 + i]));
    }
    int d = deg_row[i];
    dinv[i] = d > 0 ? rsqrtf((float)d) : 0.f;
}

// two independent exclusive scans: block 0 = col degrees, block 1 = row degrees
__global__ __launch_bounds__(256) void k_scan2(const int* __restrict__ deg_col, int* __restrict__ col_off, int* __restrict__ curC,
                                               const int* __restrict__ deg_row, int* __restrict__ row_off, int* __restrict__ curR) {
    const int* deg = (blockIdx.x == 0) ? deg_col : deg_row;
    int* off = (blockIdx.x == 0) ? col_off : row_off;
    int* cur = (blockIdx.x == 0) ? curC : curR;
    __shared__ int sd[256];
    int t = threadIdx.x;
    int base_i = t * 32;
    int loc[32];
    int s = 0;
#pragma unroll
    for (int q = 0; q < 32; q++) { loc[q] = deg[base_i + q]; s += loc[q]; }
    sd[t] = s;
    __syncthreads();
    for (int d = 1; d < 256; d <<= 1) {
        int v = (t >= d) ? sd[t - d] : 0;
        __syncthreads();
        sd[t] += v;
        __syncthreads();
    }
    int acc = sd[t] - s; // exclusive
#pragma unroll
    for (int q = 0; q < 32; q++) { off[base_i + q] = acc; cur[base_i + q] = acc; acc += loc[q]; }
    if (t == 255) off[NN] = acc;
}

// fill both CSRs
__global__ __launch_bounds__(256) void k_fill(const int* __restrict__ ei, int* __restrict__ curC,
                                              int* __restrict__ csr_row, int* __restrict__ csr_eid,
                                              int* __restrict__ curR, int* __restrict__ csrR_col,
                                              int* __restrict__ csrR_eid) {
    int e = blockIdx.x * 256 + threadIdx.x;
    int r = ei[e], c = ei[NE + e];
    int pos = atomicAdd(&curC[c], 1);
    csr_row[pos] = r;
    csr_eid[pos] = e;
    int posR = atomicAdd(&curR[r], 1);
    csrR_col[posR] = c;
    csrR_eid[posR] = e;
}

// GAT aggregate + bias + ELU + LayerNorm -> h1
// float4 accumulators: lane owns channels 4*lane..4*lane+3; 4 waves split each 64-edge chunk.
__global__ __launch_bounds__(256) void k_gat(const int* __restrict__ col_off, const int* __restrict__ csr_row,
                                             const int* __restrict__ csr_eid,
                                             const float* __restrict__ alpha, const float* __restrict__ aeloop,
                                             const float* __restrict__ a_src, const float* __restrict__ a_dst,
                                             const float* __restrict__ xs, const float* __restrict__ gat_bias,
                                             const float* __restrict__ g, const float* __restrict__ b,
                                             float* __restrict__ h1) {
    int i = blockIdx.x, t = threadIdx.x, h = t >> 6, lane = t & 63, w = t >> 6;
    int beg = col_off[i], end = col_off[i + 1];
    __shared__ float m_s[4], s_s[4], red[8];
    __shared__ float wl[64][5];       // [edge-in-chunk][head], padded
    __shared__ float accL[4 * 260];   // per-wave partial acc, padded stride 260
    // --- softmax prologue (per head h = t>>6) ---
    float sl = a_src[i * 4 + h] + a_dst[i * 4 + h] + aeloop[h];
    sl = sl > 0.f ? sl : 0.2f * sl;
    float mx = sl;
    for (int p = beg + lane; p < end; p += 64) mx = fmaxf(mx, alpha[(size_t)csr_eid[p] * 4 + h]);
    mx = wave_max(mx);
    float ss = (lane == 0) ? expf(sl - mx) : 0.f;
    for (int p = beg + lane; p < end; p += 64) ss += expf(alpha[(size_t)csr_eid[p] * 4 + h] - mx);
    ss = wave_sum(ss);
    if (lane == 0) { m_s[h] = mx; s_s[h] = ss; }
    __syncthreads();
    float minv = m_s[h];
    float sinv = 1.f / (s_s[h] + 1e-16f);
    // --- main loop: chunks of 64 edges; wave w consumes q = w, w+4, ... ---
    float4 acc = make_float4(0.f, 0.f, 0.f, 0.f);
    int hh = lane >> 4;               // head for this lane's 4 channels
    for (int cb = beg; cb < end; cb += 64) {
        int ce = min(cb + 64, end);
        int n = ce - cb;
        int p = cb + lane;
        if (p < ce) wl[lane][h] = expf(alpha[(size_t)csr_eid[p] * 4 + h] - minv) * sinv;
        __syncthreads();
        for (int q = w; q < n; q += 4) {
            int r = csr_row[cb + q];
            float wt = wl[q][hh];
            float4 xv = ((const float4*)(xs + (size_t)r * 256))[lane];
            acc.x = fmaf(wt, xv.x, acc.x);
            acc.y = fmaf(wt, xv.y, acc.y);
            acc.z = fmaf(wt, xv.z, acc.z);
            acc.w = fmaf(wt, xv.w, acc.w);
        }
        __syncthreads();
    }
    ((float4*)(accL + w * 260))[lane] = acc;
    __syncthreads();
    // --- epilogue: combine wave partials, add self-loop, bias+ELU+LN ---
    float v = accL[t] + accL[260 + t] + accL[520 + t] + accL[780 + t];
    float wself = expf(sl - minv) * sinv;
    v = fmaf(wself, xs[(size_t)i * 256 + t], v);
    v = eluf(v + gat_bias[t]);
    float s1 = wave_sum(v), s2 = wave_sum(v * v);
    if (lane == 0) { red[w] = s1; red[4 + w] = s2; }
    __syncthreads();
    float mu = (red[0] + red[1] + red[2] + red[3]) * (1.f / 256.f);
    float m2 = (red[4] + red[5] + red[6] + red[7]) * (1.f / 256.f);
    float var = m2 - mu * mu;
    float rs = rsqrtf(var + 1e-5f);
    h1[(size_t)i * 256 + t] = (v - mu) * rs * g[t] + b[t];
}

// A = h1 @ W1[:256] + b1 ; B = h1 @ W1[256:]  (tiled: ABNT nodes/block)
__global__ __launch_bounds__(256) void k_AB(const float* __restrict__ h1, const float* __restrict__ w1,
                                            const float* __restrict__ b1, float* __restrict__ A, float* __restrict__ B) {
    __shared__ float hl[ABNT * 256];
    int bk = blockIdx.x, t = threadIdx.x;
    size_t base = (size_t)bk * ABNT;
#pragma unroll
    for (int n = 0; n < ABNT; ++n) hl[n * 256 + t] = h1[(base + n) * 256 + t];
    __syncthreads();
    float accA[ABNT], accB[ABNT];
    float bv = b1[t];
#pragma unroll
    for (int n = 0; n < ABNT; ++n) { accA[n] = bv; accB[n] = 0.f; }
    for (int k = 0; k < 256; ++k) {
        float wa = w1[k * 256 + t];
        float wb = w1[(256 + k) * 256 + t];
#pragma unroll
        for (int n = 0; n < ABNT; ++n) {
            float hv = hl[n * 256 + k];
            accA[n] = fmaf(hv, wa, accA[n]);
            accB[n] = fmaf(hv, wb, accB[n]);
        }
    }
#pragma unroll
    for (int n = 0; n < ABNT; ++n) {
        A[(base + n) * 256 + t] = accA[n];
        B[(base + n) * 256 + t] = accB[n];
    }
}

// regularizer + gcn coefficients, ROW-stationary: wave holds A[r] in regs, gathers B[c].
__global__ __launch_bounds__(256) void k_regc(const int* __restrict__ row_off, const int* __restrict__ csrR_col,
                                              const int* __restrict__ csrR_eid,
                                              const float* __restrict__ A, const float* __restrict__ B,
                                              const float* __restrict__ w2, const float* __restrict__ b2,
                                              const float* __restrict__ dinv,
                                              const float* __restrict__ conf1, const float* __restrict__ conf2,
                                              float* __restrict__ adj, float* __restrict__ coef1,
                                              float* __restrict__ coef2) {
    int t = threadIdx.x, w = t >> 6, lane = t & 63;
    int r = blockIdx.x * 4 + w;
    float4 av = ((const float4*)(A + (size_t)r * 256))[lane];
    float4 w4 = ((const float4*)w2)[lane];
    float b2v = b2[0];
    float dr = dinv[r];
    int beg = row_off[r], end = row_off[r + 1];
    for (int p = beg; p < end; ++p) {
        int c = csrR_col[p];
        int e = csrR_eid[p];
        float4 bv = ((const float4*)(B + (size_t)c * 256))[lane];
        float v0 = eluf(av.x + bv.x), v1 = eluf(av.y + bv.y);
        float v2 = eluf(av.z + bv.z), v3 = eluf(av.w + bv.w);
        float s = fmaf(v0, w4.x, fmaf(v1, w4.y, fmaf(v2, w4.z, v3 * w4.w)));
        s = wave_sum(s);
        if (lane == 0) {
            float pv = sigmf(s + b2v);
            float adjv = 1.f;
            if (r != c) { adj[(size_t)r * NN + c] = pv; adjv = pv; }
            float base = dr * dinv[c] * 0.5f;
            coef1[e] = base * (conf1[e] + adjv);
            coef2[e] = base * (conf2[e] + adjv);
        }
    }
}

// gcn1: agg = sum coef1*h1[row] -> @ g1_lin + b -> ELU -> LN(64) -> h2. 16 nodes/block.
__global__ __launch_bounds__(256) void k_gcn1(const int* __restrict__ col_off, const int* __restrict__ csr_row,
                                              const int* __restrict__ csr_eid, const float* __restrict__ coef1,
                                              const float* __restrict__ h1, const float* __restrict__ W,
                                              const float* __restrict__ bias, const float* __restrict__ g,
                                              const float* __restrict__ bb, float* __restrict__ h2) {
    __shared__ float agg[G1NT * 260];   // padded stride
    int t = threadIdx.x, w = t >> 6, lane = t & 63;
    size_t ibase = (size_t)blockIdx.x * G1NT;
    // phase 1: aggregate 4 nodes per wave, float4 per lane
#pragma unroll
    for (int s = 0; s < 4; ++s) {
        int n = w * 4 + s;
        int i = ibase + n;
        int beg = col_off[i], end = col_off[i + 1];
        float4 acc = make_float4(0.f, 0.f, 0.f, 0.f);
        for (int p = beg; p < end; ++p) {
            float cf = coef1[csr_eid[p]];
            float4 hv = ((const float4*)(h1 + (size_t)csr_row[p] * 256))[lane];
            acc.x = fmaf(cf, hv.x, acc.x);
            acc.y = fmaf(cf, hv.y, acc.y);
            acc.z = fmaf(cf, hv.z, acc.z);
            acc.w = fmaf(cf, hv.w, acc.w);
        }
        ((float4*)(agg + n * 260))[lane] = acc;
    }
    __syncthreads();
    // phase 2: GEMV 256->64 per node; thread t: node t>>4, outputs 4*(t&15)..+3
    int n2 = t >> 4, q = t & 15;
    const float* aggn = agg + n2 * 260;
    float4 y = ((const float4*)bias)[q];
    for (int k = 0; k < 256; ++k) {
        float a = aggn[k];
        float4 wv = ((const float4*)(W + k * 64))[q];
        y.x = fmaf(a, wv.x, y.x);
        y.y = fmaf(a, wv.y, y.y);
        y.z = fmaf(a, wv.z, y.z);
        y.w = fmaf(a, wv.w, y.w);
    }
    y.x = eluf(y.x); y.y = eluf(y.y); y.z = eluf(y.z); y.w = eluf(y.w);
    float s1 = y.x + y.y + y.z + y.w;
    float s2 = y.x * y.x + y.y * y.y + y.z * y.z + y.w * y.w;
#pragma unroll
    for (int o = 1; o < 16; o <<= 1) { s1 += __shfl_xor(s1, o); s2 += __shfl_xor(s2, o); }
    float mu = s1 * (1.f / 64.f);
    float var = s2 * (1.f / 64.f) - mu * mu;
    float rs = rsqrtf(var + 1e-5f);
    float4 g4 = ((const float4*)g)[q], b4 = ((const float4*)bb)[q];
    float4 outv;
    outv.x = (y.x - mu) * rs * g4.x + b4.x;
    outv.y = (y.y - mu) * rs * g4.y + b4.y;
    outv.z = (y.z - mu) * rs * g4.z + b4.z;
    outv.w = (y.w - mu) * rs * g4.w + b4.w;
    ((float4*)(h2 + (ibase + n2) * 64))[q] = outv;
}

// gcn2 + classifier -> logits
__global__ __launch_bounds__(256) void k_gcn2(const int* __restrict__ col_off, const int* __restrict__ csr_row,
                                              const int* __restrict__ csr_eid, const float* __restrict__ coef2,
                                              const float* __restrict__ h2, const float* __restrict__ g2w,
                                              const float* __restrict__ g2b, const float* __restrict__ cw1,
                                              const float* __restrict__ cb1, const float* __restrict__ cw2,
                                              const float* __restrict__ cb2, float* __restrict__ out) {
    __shared__ float zl[4][64];
    __shared__ float ul[4][64];
    __shared__ float tl[4][64];
    int t = threadIdx.x, w = t >> 6, lane = t & 63;
    int i = blockIdx.x * 4 + w;
    int beg = col_off[i], end = col_off[i + 1];
    float z = 0.f;
    for (int p = beg; p < end; ++p)
        z = fmaf(coef2[csr_eid[p]], h2[(size_t)csr_row[p] * 64 + lane], z);
    zl[w][lane] = z;
    __syncthreads();
    float u = g2b[lane];
#pragma unroll 4
    for (int k = 0; k < 64; k++) u = fmaf(zl[w][k], g2w[k * 64 + lane], u);
    ul[w][lane] = u;
    __syncthreads();
    float t1 = cb1[lane];
#pragma unroll 4
    for (int k = 0; k < 64; k++) t1 = fmaf(ul[w][k], cw1[k * 64 + lane], t1);
    t1 = eluf(t1);
    tl[w][lane] = t1;
    __syncthreads();
    if (lane < 8) {
        float o = cb2[lane];
#pragma unroll 4
        for (int k = 0; k < 64; k++) o = fmaf(tl[w][k], cw2[k * 8 + lane], o);
        out[(size_t)i * 8 + lane] = o;
    }
}

// ---------------- launch ----------------
extern "C" void kernel_launch(void* const* d_in, const int* in_sizes, int n_in,
                              void* d_out, int out_size, void* d_ws, size_t ws_size,
                              hipStream_t stream) {
    const float* x           = (const float*)d_in[0];
    const float* edge_attr   = (const float*)d_in[1];
    const float* gat_lin_w   = (const float*)d_in[2];
    const float* gat_lin_edge_w = (const float*)d_in[3];
    const float* att_src     = (const float*)d_in[4];
    const float* att_dst     = (const float*)d_in[5];
    const float* att_edge    = (const float*)d_in[6];
    const float* gat_bias    = (const float*)d_in[7];
    const float* norm1_g     = (const float*)d_in[8];
    const float* norm1_b     = (const float*)d_in[9];
    const float* reg_w1      = (const float*)d_in[10];
    const float* reg_b1      = (const float*)d_in[11];
    const float* reg_w2      = (const float*)d_in[12];
    const float* reg_b2      = (const float*)d_in[13];
    const float* g1_lin_w    = (const float*)d_in[14];
    const float* g1_lin_b    = (const float*)d_in[15];
    const float* g1_conf_w   = (const float*)d_in[16];
    const float* g1_conf_b   = (const float*)d_in[17];
    const float* norm2_g     = (const float*)d_in[18];
    const float* norm2_b     = (const float*)d_in[19];
    const float* g2_lin_w    = (const float*)d_in[20];
    const float* g2_lin_b    = (const float*)d_in[21];
    const float* g2_conf_w   = (const float*)d_in[22];
    const float* g2_conf_b   = (const float*)d_in[23];
    const float* cls_w1      = (const float*)d_in[24];
    const float* cls_b1      = (const float*)d_in[25];
    const float* cls_w2      = (const float*)d_in[26];
    const float* cls_b2      = (const float*)d_in[27];
    const int*   edge_index  = (const int*)d_in[28];

    float* out = (float*)d_out;
    float* adj = out + (size_t)NN * NCLS;

    float* wsf   = (float*)d_ws;
    float* xs    = wsf + OFF_XS;
    float* a_src = wsf + OFF_ASRC;
    float* a_dst = wsf + OFF_ADST;
    float* alpha = wsf + OFF_ALPHA;
    float* conf1 = wsf + OFF_CONF1;
    float* conf2 = wsf + OFF_CONF2;
    float* coef1 = wsf + OFF_COEF1;
    float* coef2 = wsf + OFF_COEF2;
    float* h1    = wsf + OFF_H1;
    float* A     = wsf + OFF_A;
    float* B     = wsf + OFF_B;
    float* h2    = wsf + OFF_H2;
    float* dinv  = wsf + OFF_DINV;
    float* sum_ea= wsf + OFF_SUMEA;
    float* M     = wsf + OFF_M;
    float* aeloop= wsf + OFF_AELOOP;
    int* ib      = (int*)(wsf + OFF_INT);
    int* deg_col = ib + IOFF_DEGC;
    int* deg_row = ib + IOFF_DEGR;
    int* col_off = ib + IOFF_COLOFF;
    int* curC    = ib + IOFF_CURC;
    int* row_off = ib + IOFF_ROWOFF;
    int* curR    = ib + IOFF_CURR;
    int* csr_row = ib + IOFF_CSR_ROW;
    int* csr_eid = ib + IOFF_CSR_EID;
    int* csrR_col= ib + IOFF_CSRR_COL;
    int* csrR_eid= ib + IOFF_CSRR_EID;

    // 1. zero adj (268 MB) via fill engine; then init (diag, counters, M)
    hipMemsetAsync(adj, 0, (size_t)NN * NN * sizeof(float), stream);
    k_init<<<NN / 256, 256, 0, stream>>>(deg_col, deg_row, sum_ea, adj,
                                         gat_lin_edge_w, att_edge, M);
    // 2. node transform xs (tiled), attention src/dst logits
    k_node<<<NN / NDNT, 256, 0, stream>>>(x, gat_lin_w, att_src, att_dst, xs, a_src, a_dst);
    // 3. per-edge: alpha logits, conf sigmoids, degree counts, edge_attr sums
    k_edge<<<NE / 256, 256, 0, stream>>>(edge_index, edge_attr, M, a_src, a_dst,
                                         g1_conf_w, g1_conf_b, g2_conf_w, g2_conf_b,
                                         alpha, conf1, conf2, deg_col, deg_row, sum_ea);
    // 4. self-loop logit constant + dinv
    k_loopdinv<<<NN / 256, 256, 0, stream>>>(sum_ea, M, aeloop, deg_row, dinv);
    // 5. CSR build (both col- and row-keyed)
    k_scan2<<<2, 256, 0, stream>>>(deg_col, col_off, curC, deg_row, row_off, curR);
    k_fill<<<NE / 256, 256, 0, stream>>>(edge_index, curC, csr_row, csr_eid, curR, csrR_col, csrR_eid);
    // 6. GAT aggregate + ELU + LN -> h1
    k_gat<<<NN, 256, 0, stream>>>(col_off, csr_row, csr_eid, alpha, aeloop, a_src, a_dst,
                                  xs, gat_bias, norm1_g, norm1_b, h1);
    // 7. regularizer factored GEMMs (tiled)
    k_AB<<<NN / ABNT, 256, 0, stream>>>(h1, reg_w1, reg_b1, A, B);
    // 8. per-edge prob + adj scatter + gcn coefficients (row-stationary)
    k_regc<<<NN / 4, 256, 0, stream>>>(row_off, csrR_col, csrR_eid, A, B, reg_w2, reg_b2,
                                       dinv, conf1, conf2, adj, coef1, coef2);
    // 9. gcn1 -> h2
    k_gcn1<<<NN / G1NT, 256, 0, stream>>>(col_off, csr_row, csr_eid, coef1, h1,
                                          g1_lin_w, g1_lin_b, norm2_g, norm2_b, h2);
    // 10. gcn2 + classifier -> logits
    k_gcn2<<<NN / 4, 256, 0, stream>>>(col_off, csr_row, csr_eid, coef2, h2,
                                       g2_lin_w, g2_lin_b, cls_w1, cls_b1, cls_w2, cls_b2, out);
    (void)in_sizes; (void)n_in; (void)out_size; (void)ws_size;
}

// Round 8
// 832.135 us; speedup vs baseline: 1.0867x; 1.0867x over previous
//
#include <hip/hip_runtime.h>
#include <hip/hip_fp16.h>
#include <math.h>

#define NN 8192
#define NE 262144
#define FIN 128
#define HC 256
#define CC 64
#define NCLS 8
#define NDNT 16   // nodes per block in k_node
#define ABNT 16   // nodes per block in k_AB

// ---------------- ws layout (float-unit offsets; fp16 regions use half the space) ----------------
constexpr size_t OFF_XS    = 0;                              // N*256 (fp16, region sized for f32)
constexpr size_t OFF_ASRC  = OFF_XS + (size_t)NN * 256;      // N*4
constexpr size_t OFF_ADST  = OFF_ASRC + (size_t)NN * 4;      // N*4
constexpr size_t OFF_ALPHA = OFF_ADST + (size_t)NN * 4;      // E*4
constexpr size_t OFF_CONF1 = OFF_ALPHA + (size_t)NE * 4;     // E
constexpr size_t OFF_CONF2 = OFF_CONF1 + (size_t)NE;         // E
constexpr size_t OFF_COEF1 = OFF_CONF2 + (size_t)NE;         // E
constexpr size_t OFF_COEF2 = OFF_COEF1 + (size_t)NE;         // E
constexpr size_t OFF_H1    = OFF_COEF2 + (size_t)NE;         // N*256 (fp16)
constexpr size_t OFF_A     = OFF_H1 + (size_t)NN * 256;      // N*256 (fp16)
constexpr size_t OFF_B     = OFF_A + (size_t)NN * 256;       // N*256 (fp16)
constexpr size_t OFF_H2    = OFF_B + (size_t)NN * 256;       // N*64 (f32)
constexpr size_t OFF_DINV  = OFF_H2 + (size_t)NN * 64;       // N
constexpr size_t OFF_SUMEA = OFF_DINV + (size_t)NN;          // 4 (3 used)
constexpr size_t OFF_M     = OFF_SUMEA + 4;                  // 12
constexpr size_t OFF_AELOOP= OFF_M + 12;                     // 4
constexpr size_t OFF_INT   = OFF_AELOOP + 4;                 // ints from here
constexpr size_t IOFF_DEGC   = 0;                 // NN
constexpr size_t IOFF_DEGR   = IOFF_DEGC + NN;    // NN
constexpr size_t IOFF_COLOFF = IOFF_DEGR + NN;    // NN+1
constexpr size_t IOFF_CURSOR = IOFF_COLOFF + NN + 1; // NN
constexpr size_t IOFF_CSRROW = IOFF_CURSOR + NN;  // NE
constexpr size_t IOFF_CSREID = IOFF_CSRROW + NE;  // NE

struct alignas(8) Half4 { __half2 a, b; };
__device__ __forceinline__ float4 h4tof4(Half4 v) {
    float2 lo = __half22float2(v.a), hi = __half22float2(v.b);
    return make_float4(lo.x, lo.y, hi.x, hi.y);
}

// ---------------- helpers ----------------
__device__ __forceinline__ float wave_sum(float v) {
    for (int o = 32; o; o >>= 1) v += __shfl_xor(v, o);
    return v;
}
__device__ __forceinline__ float wave_max(float v) {
    for (int o = 32; o; o >>= 1) v = fmaxf(v, __shfl_xor(v, o));
    return v;
}
__device__ __forceinline__ float eluf(float v) { return v > 0.f ? v : (expf(v) - 1.f); }
__device__ __forceinline__ float sigmf(float v) { return 1.f / (1.f + expf(-v)); }

// ---------------- kernels ----------------
// zero counters, set adj diag (after memset in stream order), compute M[3][4]
__global__ __launch_bounds__(256) void k_init(int* deg_col, int* deg_row, float* sum_ea,
                                              float* adj, const float* lew,
                                              const float* att_edge, float* M) {
    int i = blockIdx.x * blockDim.x + threadIdx.x;
    deg_col[i] = 0;
    deg_row[i] = 0;
    adj[(size_t)i * NN + i] = 1.f;
    if (i < 3) sum_ea[i] = 0.f;
    if (i < 12) {
        int d = i >> 2, h = i & 3;
        float s = 0.f;
        for (int c = 0; c < 64; c++) s = fmaf(lew[d * 256 + h * 64 + c], att_edge[h * 64 + c], s);
        M[i] = s; // M[d*4+h]
    }
}

// xs = x @ gat_lin_w (fp16 out); a_src/a_dst per (node, head). Tiled: NDNT nodes/block.
__global__ __launch_bounds__(256) void k_node(const float* __restrict__ x, const float* __restrict__ W,
                                              const float* __restrict__ att_src, const float* __restrict__ att_dst,
                                              __half* __restrict__ xs, float* __restrict__ a_src, float* __restrict__ a_dst) {
    __shared__ float xl[NDNT * FIN];
    int b = blockIdx.x, t = threadIdx.x;
    size_t base = (size_t)b * NDNT;
#pragma unroll
    for (int q = 0; q < NDNT * FIN / 256; ++q) {
        int idx = q * 256 + t;
        xl[idx] = x[base * FIN + idx];
    }
    __syncthreads();
    float acc[NDNT];
#pragma unroll
    for (int n = 0; n < NDNT; ++n) acc[n] = 0.f;
    for (int k = 0; k < FIN; ++k) {
        float wv = W[k * 256 + t];
#pragma unroll
        for (int n = 0; n < NDNT; ++n) acc[n] = fmaf(xl[n * FIN + k], wv, acc[n]);
    }
    float as = att_src[t], ad = att_dst[t];
#pragma unroll
    for (int n = 0; n < NDNT; ++n) {
        xs[(base + n) * 256 + t] = __float2half_rn(acc[n]);
        float ps = wave_sum(acc[n] * as);
        float pd = wave_sum(acc[n] * ad);
        if ((t & 63) == 0) {
            a_src[(base + n) * 4 + (t >> 6)] = ps;
            a_dst[(base + n) * 4 + (t >> 6)] = pd;
        }
    }
}

__global__ __launch_bounds__(256) void k_edge(const int* __restrict__ ei, const float* __restrict__ eattr,
                                              const float* __restrict__ M,
                                              const float* __restrict__ a_src, const float* __restrict__ a_dst,
                                              const float* __restrict__ c1w, const float* __restrict__ c1b,
                                              const float* __restrict__ c2w, const float* __restrict__ c2b,
                                              float* __restrict__ alpha, float* __restrict__ conf1, float* __restrict__ conf2,
                                              int* __restrict__ deg_col, int* __restrict__ deg_row, float* __restrict__ sum_ea) {
    int e = blockIdx.x * 256 + threadIdx.x;
    int r = ei[e], c = ei[NE + e];
    float ea0 = eattr[e * 3 + 0], ea1 = eattr[e * 3 + 1], ea2 = eattr[e * 3 + 2];
#pragma unroll
    for (int h = 0; h < 4; h++) {
        float ae = fmaf(ea0, M[0 * 4 + h], fmaf(ea1, M[1 * 4 + h], ea2 * M[2 * 4 + h]));
        float v = a_src[r * 4 + h] + a_dst[c * 4 + h] + ae;
        alpha[(size_t)e * 4 + h] = v > 0.f ? v : 0.2f * v;
    }
    conf1[e] = sigmf(fmaf(ea0, c1w[0], fmaf(ea1, c1w[1], fmaf(ea2, c1w[2], c1b[0]))));
    conf2[e] = sigmf(fmaf(ea0, c2w[0], fmaf(ea1, c2w[1], fmaf(ea2, c2w[2], c2b[0]))));
    atomicAdd(&deg_col[c], 1);
    atomicAdd(&deg_row[r], 1);
    float s0 = wave_sum(ea0), s1 = wave_sum(ea1), s2 = wave_sum(ea2);
    if ((threadIdx.x & 63) == 0) {
        atomicAdd(&sum_ea[0], s0); atomicAdd(&sum_ea[1], s1); atomicAdd(&sum_ea[2], s2);
    }
}

// self-loop logit constant + dinv
__global__ __launch_bounds__(256) void k_loopdinv(const float* sum_ea, const float* M, float* aeloop,
                                                  const int* deg_row, float* dinv) {
    int i = blockIdx.x * blockDim.x + threadIdx.x;
    if (i < 4) {
        float m0 = sum_ea[0] * (1.f / NE), m1 = sum_ea[1] * (1.f / NE), m2 = sum_ea[2] * (1.f / NE);
        aeloop[i] = fmaf(m0, M[0 * 4 + i], fmaf(m1, M[1 * 4 + i], m2 * M[2 * 4 + i]));
    }
    int d = deg_row[i];
    dinv[i] = d > 0 ? rsqrtf((float)d) : 0.f;
}

__global__ __launch_bounds__(256) void k_scan(const int* __restrict__ deg_col, int* __restrict__ col_off, int* __restrict__ cursor) {
    __shared__ int sd[256];
    int t = threadIdx.x;
    int base_i = t * 32;
    int loc[32];
    int s = 0;
#pragma unroll
    for (int q = 0; q < 32; q++) { loc[q] = deg_col[base_i + q]; s += loc[q]; }
    sd[t] = s;
    __syncthreads();
    for (int d = 1; d < 256; d <<= 1) {
        int v = (t >= d) ? sd[t - d] : 0;
        __syncthreads();
        sd[t] += v;
        __syncthreads();
    }
    int acc = sd[t] - s; // exclusive
#pragma unroll
    for (int q = 0; q < 32; q++) { col_off[base_i + q] = acc; cursor[base_i + q] = acc; acc += loc[q]; }
    if (t == 255) col_off[NN] = acc;
}

__global__ __launch_bounds__(256) void k_fill(const int* __restrict__ ei, int* __restrict__ cursor,
                                              int* __restrict__ csr_row, int* __restrict__ csr_eid) {
    int e = blockIdx.x * 256 + threadIdx.x;
    int r = ei[e], c = ei[NE + e];
    int pos = atomicAdd(&cursor[c], 1);
    csr_row[pos] = r;
    csr_eid[pos] = e;
}

// GAT aggregate + bias + ELU + LayerNorm -> h1 (fp16 xs gathers, weights in LDS per 64-edge chunk)
__global__ __launch_bounds__(256) void k_gat(const int* __restrict__ col_off, const int* __restrict__ csr_row,
                                             const int* __restrict__ csr_eid,
                                             const float* __restrict__ alpha, const float* __restrict__ aeloop,
                                             const float* __restrict__ a_src, const float* __restrict__ a_dst,
                                             const __half* __restrict__ xs, const float* __restrict__ gat_bias,
                                             const float* __restrict__ g, const float* __restrict__ b,
                                             __half* __restrict__ h1) {
    int i = blockIdx.x, t = threadIdx.x, h = t >> 6, lane = t & 63;
    int beg = col_off[i], end = col_off[i + 1];
    __shared__ float m_s[4], s_s[4], red[8];
    __shared__ float wl[64][5];   // pad 5 to avoid bank conflicts on write
    float sl = a_src[i * 4 + h] + a_dst[i * 4 + h] + aeloop[h];
    sl = sl > 0.f ? sl : 0.2f * sl;
    float mx = sl;
    for (int p = beg + lane; p < end; p += 64) mx = fmaxf(mx, alpha[(size_t)csr_eid[p] * 4 + h]);
    mx = wave_max(mx);
    float ss = (lane == 0) ? expf(sl - mx) : 0.f;
    for (int p = beg + lane; p < end; p += 64) ss += expf(alpha[(size_t)csr_eid[p] * 4 + h] - mx);
    ss = wave_sum(ss);
    if (lane == 0) { m_s[h] = mx; s_s[h] = ss; }
    __syncthreads();
    float minv = m_s[h];
    float sinv = 1.f / (s_s[h] + 1e-16f);
    float acc = expf(sl - minv) * sinv * __half2float(xs[(size_t)i * 256 + t]);
    for (int cb = beg; cb < end; cb += 64) {
        int ce = min(cb + 64, end);
        int p = cb + lane;
        if (p < ce) wl[lane][h] = expf(alpha[(size_t)csr_eid[p] * 4 + h] - minv) * sinv;
        __syncthreads();
        int n = ce - cb;
        for (int q = 0; q < n; ++q)
            acc = fmaf(wl[q][h], __half2float(xs[(size_t)csr_row[cb + q] * 256 + t]), acc);
        __syncthreads();
    }
    float v = eluf(acc + gat_bias[t]);
    float s1 = wave_sum(v), s2 = wave_sum(v * v);
    if (lane == 0) { red[h] = s1; red[4 + h] = s2; }
    __syncthreads();
    float mu = (red[0] + red[1] + red[2] + red[3]) * (1.f / 256.f);
    float m2 = (red[4] + red[5] + red[6] + red[7]) * (1.f / 256.f);
    float var = m2 - mu * mu;
    float rs = rsqrtf(var + 1e-5f);
    h1[(size_t)i * 256 + t] = __float2half_rn((v - mu) * rs * g[t] + b[t]);
}

// A = h1 @ W1[:256] + b1 ; B = h1 @ W1[256:]  (tiled ABNT nodes/block; fp16 in/out, f32 math)
__global__ __launch_bounds__(256) void k_AB(const __half* __restrict__ h1, const float* __restrict__ w1,
                                            const float* __restrict__ b1, __half* __restrict__ A, __half* __restrict__ B) {
    __shared__ float hl[ABNT * 256];
    int bk = blockIdx.x, t = threadIdx.x;
    size_t base = (size_t)bk * ABNT;
#pragma unroll
    for (int n = 0; n < ABNT; ++n) hl[n * 256 + t] = __half2float(h1[(base + n) * 256 + t]);
    __syncthreads();
    float accA[ABNT], accB[ABNT];
    float bv = b1[t];
#pragma unroll
    for (int n = 0; n < ABNT; ++n) { accA[n] = bv; accB[n] = 0.f; }
    for (int k = 0; k < 256; ++k) {
        float wa = w1[k * 256 + t];
        float wb = w1[(256 + k) * 256 + t];
#pragma unroll
        for (int n = 0; n < ABNT; ++n) {
            float hv = hl[n * 256 + k];
            accA[n] = fmaf(hv, wa, accA[n]);
            accB[n] = fmaf(hv, wb, accB[n]);
        }
    }
#pragma unroll
    for (int n = 0; n < ABNT; ++n) {
        A[(base + n) * 256 + t] = __float2half_rn(accA[n]);
        B[(base + n) * 256 + t] = __float2half_rn(accB[n]);
    }
}

// per-edge regularizer + gcn coefficients fused (edge-parallel, fp16 A/B gathers):
// prob = sigmoid(elu(A[r]+B[c]).w2 + b2); adj scatter (skip diag); coef1/2
__global__ __launch_bounds__(256) void k_regc(const int* __restrict__ ei, const __half* __restrict__ A,
                                              const __half* __restrict__ B, const float* __restrict__ w2,
                                              const float* __restrict__ b2, const float* __restrict__ dinv,
                                              const float* __restrict__ conf1, const float* __restrict__ conf2,
                                              float* __restrict__ adj, float* __restrict__ coef1,
                                              float* __restrict__ coef2) {
    int t = threadIdx.x, lane = t & 63;
    int e = blockIdx.x * 4 + (t >> 6);
    int r = ei[e], c = ei[NE + e];
    float4 av = h4tof4(((const Half4*)(A + (size_t)r * 256))[lane]);
    float4 bv = h4tof4(((const Half4*)(B + (size_t)c * 256))[lane]);
    float4 w4 = ((const float4*)w2)[lane];
    float v0 = eluf(av.x + bv.x), v1 = eluf(av.y + bv.y), v2 = eluf(av.z + bv.z), v3 = eluf(av.w + bv.w);
    float s = fmaf(v0, w4.x, fmaf(v1, w4.y, fmaf(v2, w4.z, v3 * w4.w)));
    s = wave_sum(s);
    if (lane == 0) {
        float p = sigmf(s + b2[0]);
        float adjv;
        if (r != c) { adj[(size_t)r * NN + c] = p; adjv = p; }
        else adjv = 1.f;
        float base = dinv[r] * dinv[c] * 0.5f;
        coef1[e] = base * (conf1[e] + adjv);
        coef2[e] = base * (conf2[e] + adjv);
    }
}

// gcn1: agg = sum coef1*h1[row] (fp16 gathers) -> @ g1_lin + b -> ELU -> LN(64) -> h2
__global__ __launch_bounds__(256) void k_gcn1(const int* __restrict__ col_off, const int* __restrict__ csr_row,
                                              const int* __restrict__ csr_eid, const float* __restrict__ coef1,
                                              const __half* __restrict__ h1, const float* __restrict__ W,
                                              const float* __restrict__ bias, const float* __restrict__ g,
                                              const float* __restrict__ bb, float* __restrict__ h2) {
    __shared__ float al[256];
    __shared__ float pl[256];
    int i = blockIdx.x, t = threadIdx.x;
    int beg = col_off[i], end = col_off[i + 1];
    float agg = 0.f;
    for (int p = beg; p < end; ++p)
        agg = fmaf(coef1[csr_eid[p]], __half2float(h1[(size_t)csr_row[p] * 256 + t]), agg);
    al[t] = agg;
    __syncthreads();
    int cc = t & 63, q = t >> 6;
    float part = 0.f;
#pragma unroll 4
    for (int k = q * 64; k < q * 64 + 64; k++) part = fmaf(al[k], W[k * 64 + cc], part);
    pl[t] = part;
    __syncthreads();
    if (t < 64) {
        float y = pl[t] + pl[t + 64] + pl[t + 128] + pl[t + 192] + bias[t];
        y = eluf(y);
        float s1 = wave_sum(y), s2 = wave_sum(y * y);
        float mu = s1 * (1.f / 64.f);
        float var = s2 * (1.f / 64.f) - mu * mu;
        h2[(size_t)i * 64 + t] = (y - mu) * rsqrtf(var + 1e-5f) * g[t] + bb[t];
    }
}

// gcn2 + classifier -> logits
__global__ __launch_bounds__(256) void k_gcn2(const int* __restrict__ col_off, const int* __restrict__ csr_row,
                                              const int* __restrict__ csr_eid, const float* __restrict__ coef2,
                                              const float* __restrict__ h2, const float* __restrict__ g2w,
                                              const float* __restrict__ g2b, const float* __restrict__ cw1,
                                              const float* __restrict__ cb1, const float* __restrict__ cw2,
                                              const float* __restrict__ cb2, float* __restrict__ out) {
    __shared__ float zl[4][64];
    __shared__ float ul[4][64];
    __shared__ float tl[4][64];
    int t = threadIdx.x, w = t >> 6, lane = t & 63;
    int i = blockIdx.x * 4 + w;
    int beg = col_off[i], end = col_off[i + 1];
    float z = 0.f;
    for (int p = beg; p < end; ++p)
        z = fmaf(coef2[csr_eid[p]], h2[(size_t)csr_row[p] * 64 + lane], z);
    zl[w][lane] = z;
    __syncthreads();
    float u = g2b[lane];
#pragma unroll 4
    for (int k = 0; k < 64; k++) u = fmaf(zl[w][k], g2w[k * 64 + lane], u);
    ul[w][lane] = u;
    __syncthreads();
    float t1 = cb1[lane];
#pragma unroll 4
    for (int k = 0; k < 64; k++) t1 = fmaf(ul[w][k], cw1[k * 64 + lane], t1);
    t1 = eluf(t1);
    tl[w][lane] = t1;
    __syncthreads();
    if (lane < 8) {
        float o = cb2[lane];
#pragma unroll 4
        for (int k = 0; k < 64; k++) o = fmaf(tl[w][k], cw2[k * 8 + lane], o);
        out[(size_t)i * 8 + lane] = o;
    }
}

// ---------------- launch ----------------
extern "C" void kernel_launch(void* const* d_in, const int* in_sizes, int n_in,
                              void* d_out, int out_size, void* d_ws, size_t ws_size,
                              hipStream_t stream) {
    const float* x           = (const float*)d_in[0];
    const float* edge_attr   = (const float*)d_in[1];
    const float* gat_lin_w   = (const float*)d_in[2];
    const float* gat_lin_edge_w = (const float*)d_in[3];
    const float* att_src     = (const float*)d_in[4];
    const float* att_dst     = (const float*)d_in[5];
    const float* att_edge    = (const float*)d_in[6];
    const float* gat_bias    = (const float*)d_in[7];
    const float* norm1_g     = (const float*)d_in[8];
    const float* norm1_b     = (const float*)d_in[9];
    const float* reg_w1      = (const float*)d_in[10];
    const float* reg_b1      = (const float*)d_in[11];
    const float* reg_w2      = (const float*)d_in[12];
    const float* reg_b2      = (const float*)d_in[13];
    const float* g1_lin_w    = (const float*)d_in[14];
    const float* g1_lin_b    = (const float*)d_in[15];
    const float* g1_conf_w   = (const float*)d_in[16];
    const float* g1_conf_b   = (const float*)d_in[17];
    const float* norm2_g     = (const float*)d_in[18];
    const float* norm2_b     = (const float*)d_in[19];
    const float* g2_lin_w    = (const float*)d_in[20];
    const float* g2_lin_b    = (const float*)d_in[21];
    const float* g2_conf_w   = (const float*)d_in[22];
    const float* g2_conf_b   = (const float*)d_in[23];
    const float* cls_w1      = (const float*)d_in[24];
    const float* cls_b1      = (const float*)d_in[25];
    const float* cls_w2      = (const float*)d_in[26];
    const float* cls_b2      = (const float*)d_in[27];
    const int*   edge_index  = (const int*)d_in[28];

    float* out = (float*)d_out;
    float* adj = out + (size_t)NN * NCLS;

    float* wsf   = (float*)d_ws;
    __half* xs   = (__half*)(wsf + OFF_XS);
    float* a_src = wsf + OFF_ASRC;
    float* a_dst = wsf + OFF_ADST;
    float* alpha = wsf + OFF_ALPHA;
    float* conf1 = wsf + OFF_CONF1;
    float* conf2 = wsf + OFF_CONF2;
    float* coef1 = wsf + OFF_COEF1;
    float* coef2 = wsf + OFF_COEF2;
    __half* h1   = (__half*)(wsf + OFF_H1);
    __half* A    = (__half*)(wsf + OFF_A);
    __half* B    = (__half*)(wsf + OFF_B);
    float* h2    = wsf + OFF_H2;
    float* dinv  = wsf + OFF_DINV;
    float* sum_ea= wsf + OFF_SUMEA;
    float* M     = wsf + OFF_M;
    float* aeloop= wsf + OFF_AELOOP;
    int* ib      = (int*)(wsf + OFF_INT);
    int* deg_col = ib + IOFF_DEGC;
    int* deg_row = ib + IOFF_DEGR;
    int* col_off = ib + IOFF_COLOFF;
    int* cursor  = ib + IOFF_CURSOR;
    int* csr_row = ib + IOFF_CSRROW;
    int* csr_eid = ib + IOFF_CSREID;

    // 1. zero adj (268 MB) via fill engine; then init (diag, counters, M)
    hipMemsetAsync(adj, 0, (size_t)NN * NN * sizeof(float), stream);
    k_init<<<NN / 256, 256, 0, stream>>>(deg_col, deg_row, sum_ea, adj,
                                         gat_lin_edge_w, att_edge, M);
    // 2. node transform xs (tiled, fp16 out), attention src/dst logits
    k_node<<<NN / NDNT, 256, 0, stream>>>(x, gat_lin_w, att_src, att_dst, xs, a_src, a_dst);
    // 3. per-edge: alpha logits, conf sigmoids, degree counts, edge_attr sums
    k_edge<<<NE / 256, 256, 0, stream>>>(edge_index, edge_attr, M, a_src, a_dst,
                                         g1_conf_w, g1_conf_b, g2_conf_w, g2_conf_b,
                                         alpha, conf1, conf2, deg_col, deg_row, sum_ea);
    // 4. self-loop logit constant + dinv
    k_loopdinv<<<NN / 256, 256, 0, stream>>>(sum_ea, M, aeloop, deg_row, dinv);
    // 5. CSR build
    k_scan<<<1, 256, 0, stream>>>(deg_col, col_off, cursor);
    k_fill<<<NE / 256, 256, 0, stream>>>(edge_index, cursor, csr_row, csr_eid);
    // 6. GAT aggregate + ELU + LN -> h1 (fp16)
    k_gat<<<NN, 256, 0, stream>>>(col_off, csr_row, csr_eid, alpha, aeloop, a_src, a_dst,
                                  xs, gat_bias, norm1_g, norm1_b, h1);
    // 7. regularizer factored GEMMs (tiled, fp16 out)
    k_AB<<<NN / ABNT, 256, 0, stream>>>(h1, reg_w1, reg_b1, A, B);
    // 8. per-edge prob + adj scatter + gcn coefficients (edge-parallel, fp16 gathers)
    k_regc<<<NE / 4, 256, 0, stream>>>(edge_index, A, B, reg_w2, reg_b2, dinv,
                                       conf1, conf2, adj, coef1, coef2);
    // 9. gcn1 -> h2
    k_gcn1<<<NN, 256, 0, stream>>>(col_off, csr_row, csr_eid, coef1, h1,
                                   g1_lin_w, g1_lin_b, norm2_g, norm2_b, h2);
    // 10. gcn2 + classifier -> logits
    k_gcn2<<<NN / 4, 256, 0, stream>>>(col_off, csr_row, csr_eid, coef2, h2,
                                       g2_lin_w, g2_lin_b, cls_w1, cls_b1, cls_w2, cls_b2, out);
    (void)in_sizes; (void)n_in; (void)out_size; (void)ws_size;
}

// Round 12
// 824.404 us; speedup vs baseline: 1.0969x; 1.0094x over previous
//
#include <hip/hip_runtime.h>
#include <hip/hip_fp16.h>
#include <math.h>

#define NN 8192
#define NE 262144
#define FIN 128
#define HC 256
#define CC 64
#define NCLS 8
#define NDNT 16   // nodes per block in k_node
#define ABNT 16   // nodes per block in k_AB

// ---------------- ws layout (float-unit offsets; fp16 regions use half the space) ----------------
constexpr size_t OFF_XS    = 0;                              // N*256 (fp16, region sized for f32)
constexpr size_t OFF_ASRC  = OFF_XS + (size_t)NN * 256;      // N*4
constexpr size_t OFF_ADST  = OFF_ASRC + (size_t)NN * 4;      // N*4
constexpr size_t OFF_ALPHA = OFF_ADST + (size_t)NN * 4;      // E*4
constexpr size_t OFF_CONF1 = OFF_ALPHA + (size_t)NE * 4;     // E
constexpr size_t OFF_CONF2 = OFF_CONF1 + (size_t)NE;         // E
constexpr size_t OFF_COEF1 = OFF_CONF2 + (size_t)NE;         // E
constexpr size_t OFF_COEF2 = OFF_COEF1 + (size_t)NE;         // E
constexpr size_t OFF_H1    = OFF_COEF2 + (size_t)NE;         // N*256 (fp16)
constexpr size_t OFF_A     = OFF_H1 + (size_t)NN * 256;      // N*256 (fp16)
constexpr size_t OFF_B     = OFF_A + (size_t)NN * 256;       // N*256 (fp16)
constexpr size_t OFF_H2    = OFF_B + (size_t)NN * 256;       // N*64 (f32)
constexpr size_t OFF_DINV  = OFF_H2 + (size_t)NN * 64;       // N
constexpr size_t OFF_SUMEA = OFF_DINV + (size_t)NN;          // 4 (3 used)
constexpr size_t OFF_M     = OFF_SUMEA + 4;                  // 12
constexpr size_t OFF_AELOOP= OFF_M + 12;                     // 4
constexpr size_t OFF_INT   = OFF_AELOOP + 4;                 // ints from here
constexpr size_t IOFF_DEGC   = 0;                 // NN
constexpr size_t IOFF_DEGR   = IOFF_DEGC + NN;    // NN
constexpr size_t IOFF_COLOFF = IOFF_DEGR + NN;    // NN+1
constexpr size_t IOFF_CURSOR = IOFF_COLOFF + NN + 1; // NN
constexpr size_t IOFF_CSRROW = IOFF_CURSOR + NN;  // NE
constexpr size_t IOFF_CSREID = IOFF_CSRROW + NE;  // NE

struct alignas(8) Half4 { __half2 a, b; };
__device__ __forceinline__ float4 h4tof4(Half4 v) {
    float2 lo = __half22float2(v.a), hi = __half22float2(v.b);
    return make_float4(lo.x, lo.y, hi.x, hi.y);
}

// ---------------- helpers ----------------
__device__ __forceinline__ float wave_sum(float v) {
    for (int o = 32; o; o >>= 1) v += __shfl_xor(v, o);
    return v;
}
__device__ __forceinline__ float wave_max(float v) {
    for (int o = 32; o; o >>= 1) v = fmaxf(v, __shfl_xor(v, o));
    return v;
}
__device__ __forceinline__ float eluf(float v) { return v > 0.f ? v : (expf(v) - 1.f); }
__device__ __forceinline__ float sigmf(float v) { return 1.f / (1.f + expf(-v)); }

// ---------------- kernels ----------------
// zero counters, set adj diag (after memset in stream order), compute M[3][4]
__global__ __launch_bounds__(256) void k_init(int* deg_col, int* deg_row, float* sum_ea,
                                              float* adj, const float* lew,
                                              const float* att_edge, float* M) {
    int i = blockIdx.x * blockDim.x + threadIdx.x;
    deg_col[i] = 0;
    deg_row[i] = 0;
    adj[(size_t)i * NN + i] = 1.f;
    if (i < 3) sum_ea[i] = 0.f;
    if (i < 12) {
        int d = i >> 2, h = i & 3;
        float s = 0.f;
        for (int c = 0; c < 64; c++) s = fmaf(lew[d * 256 + h * 64 + c], att_edge[h * 64 + c], s);
        M[i] = s; // M[d*4+h]
    }
}

// xs = x @ gat_lin_w (fp16 out); a_src/a_dst per (node, head). Tiled: NDNT nodes/block.
__global__ __launch_bounds__(256) void k_node(const float* __restrict__ x, const float* __restrict__ W,
                                              const float* __restrict__ att_src, const float* __restrict__ att_dst,
                                              __half* __restrict__ xs, float* __restrict__ a_src, float* __restrict__ a_dst) {
    __shared__ float xl[NDNT * FIN];
    int b = blockIdx.x, t = threadIdx.x;
    size_t base = (size_t)b * NDNT;
#pragma unroll
    for (int q = 0; q < NDNT * FIN / 256; ++q) {
        int idx = q * 256 + t;
        xl[idx] = x[base * FIN + idx];
    }
    __syncthreads();
    float acc[NDNT];
#pragma unroll
    for (int n = 0; n < NDNT; ++n) acc[n] = 0.f;
    for (int k = 0; k < FIN; ++k) {
        float wv = W[k * 256 + t];
#pragma unroll
        for (int n = 0; n < NDNT; ++n) acc[n] = fmaf(xl[n * FIN + k], wv, acc[n]);
    }
    float as = att_src[t], ad = att_dst[t];
#pragma unroll
    for (int n = 0; n < NDNT; ++n) {
        xs[(base + n) * 256 + t] = __float2half_rn(acc[n]);
        float ps = wave_sum(acc[n] * as);
        float pd = wave_sum(acc[n] * ad);
        if ((t & 63) == 0) {
            a_src[(base + n) * 4 + (t >> 6)] = ps;
            a_dst[(base + n) * 4 + (t >> 6)] = pd;
        }
    }
}

__global__ __launch_bounds__(256) void k_edge(const int* __restrict__ ei, const float* __restrict__ eattr,
                                              const float* __restrict__ M,
                                              const float* __restrict__ a_src, const float* __restrict__ a_dst,
                                              const float* __restrict__ c1w, const float* __restrict__ c1b,
                                              const float* __restrict__ c2w, const float* __restrict__ c2b,
                                              float* __restrict__ alpha, float* __restrict__ conf1, float* __restrict__ conf2,
                                              int* __restrict__ deg_col, int* __restrict__ deg_row, float* __restrict__ sum_ea) {
    int e = blockIdx.x * 256 + threadIdx.x;
    int r = ei[e], c = ei[NE + e];
    float ea0 = eattr[e * 3 + 0], ea1 = eattr[e * 3 + 1], ea2 = eattr[e * 3 + 2];
#pragma unroll
    for (int h = 0; h < 4; h++) {
        float ae = fmaf(ea0, M[0 * 4 + h], fmaf(ea1, M[1 * 4 + h], ea2 * M[2 * 4 + h]));
        float v = a_src[r * 4 + h] + a_dst[c * 4 + h] + ae;
        alpha[(size_t)e * 4 + h] = v > 0.f ? v : 0.2f * v;
    }
    conf1[e] = sigmf(fmaf(ea0, c1w[0], fmaf(ea1, c1w[1], fmaf(ea2, c1w[2], c1b[0]))));
    conf2[e] = sigmf(fmaf(ea0, c2w[0], fmaf(ea1, c2w[1], fmaf(ea2, c2w[2], c2b[0]))));
    atomicAdd(&deg_col[c], 1);
    atomicAdd(&deg_row[r], 1);
    float s0 = wave_sum(ea0), s1 = wave_sum(ea1), s2 = wave_sum(ea2);
    if ((threadIdx.x & 63) == 0) {
        atomicAdd(&sum_ea[0], s0); atomicAdd(&sum_ea[1], s1); atomicAdd(&sum_ea[2], s2);
    }
}

// self-loop logit constant + dinv
__global__ __launch_bounds__(256) void k_loopdinv(const float* sum_ea, const float* M, float* aeloop,
                                                  const int* deg_row, float* dinv) {
    int i = blockIdx.x * blockDim.x + threadIdx.x;
    if (i < 4) {
        float m0 = sum_ea[0] * (1.f / NE), m1 = sum_ea[1] * (1.f / NE), m2 = sum_ea[2] * (1.f / NE);
        aeloop[i] = fmaf(m0, M[0 * 4 + i], fmaf(m1, M[1 * 4 + i], m2 * M[2 * 4 + i]));
    }
    int d = deg_row[i];
    dinv[i] = d > 0 ? rsqrtf((float)d) : 0.f;
}

__global__ __launch_bounds__(256) void k_scan(const int* __restrict__ deg_col, int* __restrict__ col_off, int* __restrict__ cursor) {
    __shared__ int sd[256];
    int t = threadIdx.x;
    int base_i = t * 32;
    int loc[32];
    int s = 0;
#pragma unroll
    for (int q = 0; q < 32; q++) { loc[q] = deg_col[base_i + q]; s += loc[q]; }
    sd[t] = s;
    __syncthreads();
    for (int d = 1; d < 256; d <<= 1) {
        int v = (t >= d) ? sd[t - d] : 0;
        __syncthreads();
        sd[t] += v;
        __syncthreads();
    }
    int acc = sd[t] - s; // exclusive
#pragma unroll
    for (int q = 0; q < 32; q++) { col_off[base_i + q] = acc; cursor[base_i + q] = acc; acc += loc[q]; }
    if (t == 255) col_off[NN] = acc;
}

__global__ __launch_bounds__(256) void k_fill(const int* __restrict__ ei, int* __restrict__ cursor,
                                              int* __restrict__ csr_row, int* __restrict__ csr_eid) {
    int e = blockIdx.x * 256 + threadIdx.x;
    int r = ei[e], c = ei[NE + e];
    int pos = atomicAdd(&cursor[c], 1);
    csr_row[pos] = r;
    csr_eid[pos] = e;
}

// GAT aggregate + bias + ELU + LayerNorm -> h1
// Half4 gathers: lane owns channels 4*lane..4*lane+3 (one 512B row per wave-instruction);
// 4 waves split each 64-edge chunk; partials combined in LDS. (R7-proven structure.)
__global__ __launch_bounds__(256) void k_gat(const int* __restrict__ col_off, const int* __restrict__ csr_row,
                                             const int* __restrict__ csr_eid,
                                             const float* __restrict__ alpha, const float* __restrict__ aeloop,
                                             const float* __restrict__ a_src, const float* __restrict__ a_dst,
                                             const __half* __restrict__ xs, const float* __restrict__ gat_bias,
                                             const float* __restrict__ g, const float* __restrict__ b,
                                             __half* __restrict__ h1) {
    int i = blockIdx.x, t = threadIdx.x, h = t >> 6, lane = t & 63, w = t >> 6;
    int beg = col_off[i], end = col_off[i + 1];
    __shared__ float m_s[4], s_s[4], red[8];
    __shared__ float wl[64][5];       // [edge-in-chunk][head], padded
    __shared__ float accL[4 * 260];   // per-wave partial acc, padded stride 260
    // --- softmax prologue (per head h = t>>6) ---
    float sl = a_src[i * 4 + h] + a_dst[i * 4 + h] + aeloop[h];
    sl = sl > 0.f ? sl : 0.2f * sl;
    float mx = sl;
    for (int p = beg + lane; p < end; p += 64) mx = fmaxf(mx, alpha[(size_t)csr_eid[p] * 4 + h]);
    mx = wave_max(mx);
    float ss = (lane == 0) ? expf(sl - mx) : 0.f;
    for (int p = beg + lane; p < end; p += 64) ss += expf(alpha[(size_t)csr_eid[p] * 4 + h] - mx);
    ss = wave_sum(ss);
    if (lane == 0) { m_s[h] = mx; s_s[h] = ss; }
    __syncthreads();
    float minv = m_s[h];
    float sinv = 1.f / (s_s[h] + 1e-16f);
    // --- main loop: chunks of 64 edges; wave w consumes q = w, w+4, ... ---
    float4 acc = make_float4(0.f, 0.f, 0.f, 0.f);
    int hh = lane >> 4;               // head owning this lane's 4 channels
    for (int cb = beg; cb < end; cb += 64) {
        int ce = min(cb + 64, end);
        int n = ce - cb;
        int p = cb + lane;
        if (p < ce) wl[lane][h] = expf(alpha[(size_t)csr_eid[p] * 4 + h] - minv) * sinv;
        __syncthreads();
        for (int q = w; q < n; q += 4) {
            int r = csr_row[cb + q];
            float wt = wl[q][hh];
            float4 xv = h4tof4(((const Half4*)(xs + (size_t)r * 256))[lane]);
            acc.x = fmaf(wt, xv.x, acc.x);
            acc.y = fmaf(wt, xv.y, acc.y);
            acc.z = fmaf(wt, xv.z, acc.z);
            acc.w = fmaf(wt, xv.w, acc.w);
        }
        __syncthreads();
    }
    ((float4*)(accL + w * 260))[lane] = acc;
    __syncthreads();
    // --- epilogue: combine wave partials, add self-loop, bias+ELU+LN ---
    float v = accL[t] + accL[260 + t] + accL[520 + t] + accL[780 + t];
    float wself = expf(sl - minv) * sinv;
    v = fmaf(wself, __half2float(xs[(size_t)i * 256 + t]), v);
    v = eluf(v + gat_bias[t]);
    float s1 = wave_sum(v), s2 = wave_sum(v * v);
    if (lane == 0) { red[w] = s1; red[4 + w] = s2; }
    __syncthreads();
    float mu = (red[0] + red[1] + red[2] + red[3]) * (1.f / 256.f);
    float m2 = (red[4] + red[5] + red[6] + red[7]) * (1.f / 256.f);
    float var = m2 - mu * mu;
    float rs = rsqrtf(var + 1e-5f);
    h1[(size_t)i * 256 + t] = __float2half_rn((v - mu) * rs * g[t] + b[t]);
}

// A = h1 @ W1[:256] + b1 ; B = h1 @ W1[256:]  (tiled ABNT nodes/block; fp16 in/out, f32 math)
__global__ __launch_bounds__(256) void k_AB(const __half* __restrict__ h1, const float* __restrict__ w1,
                                            const float* __restrict__ b1, __half* __restrict__ A, __half* __restrict__ B) {
    __shared__ float hl[ABNT * 256];
    int bk = blockIdx.x, t = threadIdx.x;
    size_t base = (size_t)bk * ABNT;
#pragma unroll
    for (int n = 0; n < ABNT; ++n) hl[n * 256 + t] = __half2float(h1[(base + n) * 256 + t]);
    __syncthreads();
    float accA[ABNT], accB[ABNT];
    float bv = b1[t];
#pragma unroll
    for (int n = 0; n < ABNT; ++n) { accA[n] = bv; accB[n] = 0.f; }
    for (int k = 0; k < 256; ++k) {
        float wa = w1[k * 256 + t];
        float wb = w1[(256 + k) * 256 + t];
#pragma unroll
        for (int n = 0; n < ABNT; ++n) {
            float hv = hl[n * 256 + k];
            accA[n] = fmaf(hv, wa, accA[n]);
            accB[n] = fmaf(hv, wb, accB[n]);
        }
    }
#pragma unroll
    for (int n = 0; n < ABNT; ++n) {
        A[(base + n) * 256 + t] = __float2half_rn(accA[n]);
        B[(base + n) * 256 + t] = __float2half_rn(accB[n]);
    }
}

// per-edge regularizer + gcn coefficients fused (edge-parallel, Half4 A/B gathers):
// prob = sigmoid(elu(A[r]+B[c]).w2 + b2); adj scatter (skip diag); coef1/2
__global__ __launch_bounds__(256) void k_regc(const int* __restrict__ ei, const __half* __restrict__ A,
                                              const __half* __restrict__ B, const float* __restrict__ w2,
                                              const float* __restrict__ b2, const float* __restrict__ dinv,
                                              const float* __restrict__ conf1, const float* __restrict__ conf2,
                                              float* __restrict__ adj, float* __restrict__ coef1,
                                              float* __restrict__ coef2) {
    int t = threadIdx.x, lane = t & 63;
    int e = blockIdx.x * 4 + (t >> 6);
    int r = ei[e], c = ei[NE + e];
    float4 av = h4tof4(((const Half4*)(A + (size_t)r * 256))[lane]);
    float4 bv = h4tof4(((const Half4*)(B + (size_t)c * 256))[lane]);
    float4 w4 = ((const float4*)w2)[lane];
    float v0 = eluf(av.x + bv.x), v1 = eluf(av.y + bv.y), v2 = eluf(av.z + bv.z), v3 = eluf(av.w + bv.w);
    float s = fmaf(v0, w4.x, fmaf(v1, w4.y, fmaf(v2, w4.z, v3 * w4.w)));
    s = wave_sum(s);
    if (lane == 0) {
        float p = sigmf(s + b2[0]);
        float adjv;
        if (r != c) { adj[(size_t)r * NN + c] = p; adjv = p; }
        else adjv = 1.f;
        float base = dinv[r] * dinv[c] * 0.5f;
        coef1[e] = base * (conf1[e] + adjv);
        coef2[e] = base * (conf2[e] + adjv);
    }
}

// gcn1: agg = sum coef1*h1[row] (Half4 gathers, wave-per-edge) -> GEMV 256->64 -> ELU -> LN -> h2
__global__ __launch_bounds__(256) void k_gcn1(const int* __restrict__ col_off, const int* __restrict__ csr_row,
                                              const int* __restrict__ csr_eid, const float* __restrict__ coef1,
                                              const __half* __restrict__ h1, const float* __restrict__ W,
                                              const float* __restrict__ bias, const float* __restrict__ g,
                                              const float* __restrict__ bb, float* __restrict__ h2) {
    __shared__ float accL[4 * 260];
    __shared__ float al[256];
    __shared__ float pl[256];
    int i = blockIdx.x, t = threadIdx.x, w = t >> 6, lane = t & 63;
    int beg = col_off[i], end = col_off[i + 1];
    float4 acc = make_float4(0.f, 0.f, 0.f, 0.f);
    for (int p = beg + w; p < end; p += 4) {
        float cf = coef1[csr_eid[p]];
        float4 hv = h4tof4(((const Half4*)(h1 + (size_t)csr_row[p] * 256))[lane]);
        acc.x = fmaf(cf, hv.x, acc.x);
        acc.y = fmaf(cf, hv.y, acc.y);
        acc.z = fmaf(cf, hv.z, acc.z);
        acc.w = fmaf(cf, hv.w, acc.w);
    }
    ((float4*)(accL + w * 260))[lane] = acc;
    __syncthreads();
    al[t] = accL[t] + accL[260 + t] + accL[520 + t] + accL[780 + t];
    __syncthreads();
    int cc = t & 63, q = t >> 6;
    float part = 0.f;
#pragma unroll 4
    for (int k = q * 64; k < q * 64 + 64; k++) part = fmaf(al[k], W[k * 64 + cc], part);
    pl[t] = part;
    __syncthreads();
    if (t < 64) {
        float y = pl[t] + pl[t + 64] + pl[t + 128] + pl[t + 192] + bias[t];
        y = eluf(y);
        float s1 = wave_sum(y), s2 = wave_sum(y * y);
        float mu = s1 * (1.f / 64.f);
        float var = s2 * (1.f / 64.f) - mu * mu;
        h2[(size_t)i * 64 + t] = (y - mu) * rsqrtf(var + 1e-5f) * g[t] + bb[t];
    }
}

// gcn2 + classifier -> logits (h2 rows are 256B f32: already one row per wave-instruction)
__global__ __launch_bounds__(256) void k_gcn2(const int* __restrict__ col_off, const int* __restrict__ csr_row,
                                              const int* __restrict__ csr_eid, const float* __restrict__ coef2,
                                              const float* __restrict__ h2, const float* __restrict__ g2w,
                                              const float* __restrict__ g2b, const float* __restrict__ cw1,
                                              const float* __restrict__ cb1, const float* __restrict__ cw2,
                                              const float* __restrict__ cb2, float* __restrict__ out) {
    __shared__ float zl[4][64];
    __shared__ float ul[4][64];
    __shared__ float tl[4][64];
    int t = threadIdx.x, w = t >> 6, lane = t & 63;
    int i = blockIdx.x * 4 + w;
    int beg = col_off[i], end = col_off[i + 1];
    float z = 0.f;
    for (int p = beg; p < end; ++p)
        z = fmaf(coef2[csr_eid[p]], h2[(size_t)csr_row[p] * 64 + lane], z);
    zl[w][lane] = z;
    __syncthreads();
    float u = g2b[lane];
#pragma unroll 4
    for (int k = 0; k < 64; k++) u = fmaf(zl[w][k], g2w[k * 64 + lane], u);
    ul[w][lane] = u;
    __syncthreads();
    float t1 = cb1[lane];
#pragma unroll 4
    for (int k = 0; k < 64; k++) t1 = fmaf(ul[w][k], cw1[k * 64 + lane], t1);
    t1 = eluf(t1);
    tl[w][lane] = t1;
    __syncthreads();
    if (lane < 8) {
        float o = cb2[lane];
#pragma unroll 4
        for (int k = 0; k < 64; k++) o = fmaf(tl[w][k], cw2[k * 8 + lane], o);
        out[(size_t)i * 8 + lane] = o;
    }
}

// ---------------- launch ----------------
extern "C" void kernel_launch(void* const* d_in, const int* in_sizes, int n_in,
                              void* d_out, int out_size, void* d_ws, size_t ws_size,
                              hipStream_t stream) {
    const float* x           = (const float*)d_in[0];
    const float* edge_attr   = (const float*)d_in[1];
    const float* gat_lin_w   = (const float*)d_in[2];
    const float* gat_lin_edge_w = (const float*)d_in[3];
    const float* att_src     = (const float*)d_in[4];
    const float* att_dst     = (const float*)d_in[5];
    const float* att_edge    = (const float*)d_in[6];
    const float* gat_bias    = (const float*)d_in[7];
    const float* norm1_g     = (const float*)d_in[8];
    const float* norm1_b     = (const float*)d_in[9];
    const float* reg_w1      = (const float*)d_in[10];
    const float* reg_b1      = (const float*)d_in[11];
    const float* reg_w2      = (const float*)d_in[12];
    const float* reg_b2      = (const float*)d_in[13];
    const float* g1_lin_w    = (const float*)d_in[14];
    const float* g1_lin_b    = (const float*)d_in[15];
    const float* g1_conf_w   = (const float*)d_in[16];
    const float* g1_conf_b   = (const float*)d_in[17];
    const float* norm2_g     = (const float*)d_in[18];
    const float* norm2_b     = (const float*)d_in[19];
    const float* g2_lin_w    = (const float*)d_in[20];
    const float* g2_lin_b    = (const float*)d_in[21];
    const float* g2_conf_w   = (const float*)d_in[22];
    const float* g2_conf_b   = (const float*)d_in[23];
    const float* cls_w1      = (const float*)d_in[24];
    const float* cls_b1      = (const float*)d_in[25];
    const float* cls_w2      = (const float*)d_in[26];
    const float* cls_b2      = (const float*)d_in[27];
    const int*   edge_index  = (const int*)d_in[28];

    float* out = (float*)d_out;
    float* adj = out + (size_t)NN * NCLS;

    float* wsf   = (float*)d_ws;
    __half* xs   = (__half*)(wsf + OFF_XS);
    float* a_src = wsf + OFF_ASRC;
    float* a_dst = wsf + OFF_ADST;
    float* alpha = wsf + OFF_ALPHA;
    float* conf1 = wsf + OFF_CONF1;
    float* conf2 = wsf + OFF_CONF2;
    float* coef1 = wsf + OFF_COEF1;
    float* coef2 = wsf + OFF_COEF2;
    __half* h1   = (__half*)(wsf + OFF_H1);
    __half* A    = (__half*)(wsf + OFF_A);
    __half* B    = (__half*)(wsf + OFF_B);
    float* h2    = wsf + OFF_H2;
    float* dinv  = wsf + OFF_DINV;
    float* sum_ea= wsf + OFF_SUMEA;
    float* M     = wsf + OFF_M;
    float* aeloop= wsf + OFF_AELOOP;
    int* ib      = (int*)(wsf + OFF_INT);
    int* deg_col = ib + IOFF_DEGC;
    int* deg_row = ib + IOFF_DEGR;
    int* col_off = ib + IOFF_COLOFF;
    int* cursor  = ib + IOFF_CURSOR;
    int* csr_row = ib + IOFF_CSRROW;
    int* csr_eid = ib + IOFF_CSREID;

    // 1. zero adj (268 MB) via fill engine; then init (diag, counters, M)
    hipMemsetAsync(adj, 0, (size_t)NN * NN * sizeof(float), stream);
    k_init<<<NN / 256, 256, 0, stream>>>(deg_col, deg_row, sum_ea, adj,
                                         gat_lin_edge_w, att_edge, M);
    // 2. node transform xs (tiled, fp16 out), attention src/dst logits
    k_node<<<NN / NDNT, 256, 0, stream>>>(x, gat_lin_w, att_src, att_dst, xs, a_src, a_dst);
    // 3. per-edge: alpha logits, conf sigmoids, degree counts, edge_attr sums
    k_edge<<<NE / 256, 256, 0, stream>>>(edge_index, edge_attr, M, a_src, a_dst,
                                         g1_conf_w, g1_conf_b, g2_conf_w, g2_conf_b,
                                         alpha, conf1, conf2, deg_col, deg_row, sum_ea);
    // 4. self-loop logit constant + dinv
    k_loopdinv<<<NN / 256, 256, 0, stream>>>(sum_ea, M, aeloop, deg_row, dinv);
    // 5. CSR build
    k_scan<<<1, 256, 0, stream>>>(deg_col, col_off, cursor);
    k_fill<<<NE / 256, 256, 0, stream>>>(edge_index, cursor, csr_row, csr_eid);
    // 6. GAT aggregate + ELU + LN -> h1 (fp16, Half4 wave-wide gathers)
    k_gat<<<NN, 256, 0, stream>>>(col_off, csr_row, csr_eid, alpha, aeloop, a_src, a_dst,
                                  xs, gat_bias, norm1_g, norm1_b, h1);
    // 7. regularizer factored GEMMs (tiled, fp16 out)
    k_AB<<<NN / ABNT, 256, 0, stream>>>(h1, reg_w1, reg_b1, A, B);
    // 8. per-edge prob + adj scatter + gcn coefficients (edge-parallel, Half4 gathers)
    k_regc<<<NE / 4, 256, 0, stream>>>(edge_index, A, B, reg_w2, reg_b2, dinv,
                                       conf1, conf2, adj, coef1, coef2);
    // 9. gcn1 -> h2 (Half4 wave-wide gathers)
    k_gcn1<<<NN, 256, 0, stream>>>(col_off, csr_row, csr_eid, coef1, h1,
                                   g1_lin_w, g1_lin_b, norm2_g, norm2_b, h2);
    // 10. gcn2 + classifier -> logits
    k_gcn2<<<NN / 4, 256, 0, stream>>>(col_off, csr_row, csr_eid, coef2, h2,
                                       g2_lin_w, g2_lin_b, cls_w1, cls_b1, cls_w2, cls_b2, out);
    (void)in_sizes; (void)n_in; (void)out_size; (void)ws_size;
}

// Round 14
// 781.468 us; speedup vs baseline: 1.1571x; 1.0549x over previous
//
#include <hip/hip_runtime.h>
#include <hip/hip_fp16.h>
#include <math.h>

#define NN 8192
#define NE 262144
#define FIN 128
#define HC 256
#define CC 64
#define NCLS 8
#define NDNT 16   // nodes per block in k_node
#define ABNT 16   // nodes per block in k_AB

// ---------------- ws layout (float-unit offsets; fp16 regions use half the space) ----------------
constexpr size_t OFF_XS    = 0;                              // N*256 (fp16, region sized for f32)
constexpr size_t OFF_ASRC  = OFF_XS + (size_t)NN * 256;      // N*4
constexpr size_t OFF_ADST  = OFF_ASRC + (size_t)NN * 4;      // N*4
constexpr size_t OFF_ALPHA = OFF_ADST + (size_t)NN * 4;      // E*4
constexpr size_t OFF_CONF1 = OFF_ALPHA + (size_t)NE * 4;     // E
constexpr size_t OFF_CONF2 = OFF_CONF1 + (size_t)NE;         // E
constexpr size_t OFF_COEF1 = OFF_CONF2 + (size_t)NE;         // E
constexpr size_t OFF_COEF2 = OFF_COEF1 + (size_t)NE;         // E
constexpr size_t OFF_H1    = OFF_COEF2 + (size_t)NE;         // N*256 (fp16)
constexpr size_t OFF_A     = OFF_H1 + (size_t)NN * 256;      // N*256 (fp16)
constexpr size_t OFF_B     = OFF_A + (size_t)NN * 256;       // N*256 (fp16)
constexpr size_t OFF_H2    = OFF_B + (size_t)NN * 256;       // N*64 (f32)
constexpr size_t OFF_DINV  = OFF_H2 + (size_t)NN * 64;       // N
constexpr size_t OFF_SUMEA = OFF_DINV + (size_t)NN;          // 4 (3 used)
constexpr size_t OFF_M     = OFF_SUMEA + 4;                  // 12
constexpr size_t OFF_AELOOP= OFF_M + 12;                     // 4
constexpr size_t OFF_INT   = OFF_AELOOP + 4;                 // ints from here
constexpr size_t IOFF_DEGC   = 0;                 // NN
constexpr size_t IOFF_DEGR   = IOFF_DEGC + NN;    // NN
constexpr size_t IOFF_COLOFF = IOFF_DEGR + NN;    // NN+1
constexpr size_t IOFF_CURSOR = IOFF_COLOFF + NN + 1; // NN
constexpr size_t IOFF_CSRROW = IOFF_CURSOR + NN;  // NE
constexpr size_t IOFF_CSREID = IOFF_CSRROW + NE;  // NE

struct alignas(8) Half4 { __half2 a, b; };
__device__ __forceinline__ float4 h4tof4(Half4 v) {
    float2 lo = __half22float2(v.a), hi = __half22float2(v.b);
    return make_float4(lo.x, lo.y, hi.x, hi.y);
}

// ---------------- helpers ----------------
__device__ __forceinline__ float wave_sum(float v) {
    for (int o = 32; o; o >>= 1) v += __shfl_xor(v, o);
    return v;
}
__device__ __forceinline__ float wave_max(float v) {
    for (int o = 32; o; o >>= 1) v = fmaxf(v, __shfl_xor(v, o));
    return v;
}
__device__ __forceinline__ float eluf(float v) { return v > 0.f ? v : (expf(v) - 1.f); }
__device__ __forceinline__ float sigmf(float v) { return 1.f / (1.f + expf(-v)); }

// ---------------- kernels ----------------
// xs = x @ gat_lin_w (fp16 out); a_src/a_dst per (node, head). Tiled: NDNT nodes/block.
// Also absorbs former k_init: zero deg counters / sum_ea, compute M (consumed by later k_edge).
__global__ __launch_bounds__(256) void k_node(const float* __restrict__ x, const float* __restrict__ W,
                                              const float* __restrict__ att_src, const float* __restrict__ att_dst,
                                              const float* __restrict__ lew, const float* __restrict__ att_edge,
                                              __half* __restrict__ xs, float* __restrict__ a_src, float* __restrict__ a_dst,
                                              int* __restrict__ deg_col, int* __restrict__ deg_row,
                                              float* __restrict__ sum_ea, float* __restrict__ M) {
    int b = blockIdx.x, t = threadIdx.x;
    int gid = b * 256 + t;
    if (gid < NN) { deg_col[gid] = 0; deg_row[gid] = 0; }
    if (gid < 3) sum_ea[gid] = 0.f;
    if (gid < 12) {
        int d = gid >> 2, h = gid & 3;
        float s = 0.f;
        for (int c = 0; c < 64; c++) s = fmaf(lew[d * 256 + h * 64 + c], att_edge[h * 64 + c], s);
        M[gid] = s; // M[d*4+h]
    }
    __shared__ float xl[NDNT * FIN];
    size_t base = (size_t)b * NDNT;
#pragma unroll
    for (int q = 0; q < NDNT * FIN / 256; ++q) {
        int idx = q * 256 + t;
        xl[idx] = x[base * FIN + idx];
    }
    __syncthreads();
    float acc[NDNT];
#pragma unroll
    for (int n = 0; n < NDNT; ++n) acc[n] = 0.f;
    for (int k = 0; k < FIN; ++k) {
        float wv = W[k * 256 + t];
#pragma unroll
        for (int n = 0; n < NDNT; ++n) acc[n] = fmaf(xl[n * FIN + k], wv, acc[n]);
    }
    float as = att_src[t], ad = att_dst[t];
#pragma unroll
    for (int n = 0; n < NDNT; ++n) {
        xs[(base + n) * 256 + t] = __float2half_rn(acc[n]);
        float ps = wave_sum(acc[n] * as);
        float pd = wave_sum(acc[n] * ad);
        if ((t & 63) == 0) {
            a_src[(base + n) * 4 + (t >> 6)] = ps;
            a_dst[(base + n) * 4 + (t >> 6)] = pd;
        }
    }
}

// per-edge logits/conf/degrees; also sets adj diag (runs after memset in stream order).
__global__ __launch_bounds__(256) void k_edge(const int* __restrict__ ei, const float* __restrict__ eattr,
                                              const float* __restrict__ M,
                                              const float* __restrict__ a_src, const float* __restrict__ a_dst,
                                              const float* __restrict__ c1w, const float* __restrict__ c1b,
                                              const float* __restrict__ c2w, const float* __restrict__ c2b,
                                              float* __restrict__ alpha, float* __restrict__ conf1, float* __restrict__ conf2,
                                              int* __restrict__ deg_col, int* __restrict__ deg_row, float* __restrict__ sum_ea,
                                              float* __restrict__ adj) {
    int e = blockIdx.x * 256 + threadIdx.x;
    if (e < NN) adj[(size_t)e * NN + e] = 1.f;
    int r = ei[e], c = ei[NE + e];
    float ea0 = eattr[e * 3 + 0], ea1 = eattr[e * 3 + 1], ea2 = eattr[e * 3 + 2];
#pragma unroll
    for (int h = 0; h < 4; h++) {
        float ae = fmaf(ea0, M[0 * 4 + h], fmaf(ea1, M[1 * 4 + h], ea2 * M[2 * 4 + h]));
        float v = a_src[r * 4 + h] + a_dst[c * 4 + h] + ae;
        alpha[(size_t)e * 4 + h] = v > 0.f ? v : 0.2f * v;
    }
    conf1[e] = sigmf(fmaf(ea0, c1w[0], fmaf(ea1, c1w[1], fmaf(ea2, c1w[2], c1b[0]))));
    conf2[e] = sigmf(fmaf(ea0, c2w[0], fmaf(ea1, c2w[1], fmaf(ea2, c2w[2], c2b[0]))));
    atomicAdd(&deg_col[c], 1);
    atomicAdd(&deg_row[r], 1);
    float s0 = wave_sum(ea0), s1 = wave_sum(ea1), s2 = wave_sum(ea2);
    if ((threadIdx.x & 63) == 0) {
        atomicAdd(&sum_ea[0], s0); atomicAdd(&sum_ea[1], s1); atomicAdd(&sum_ea[2], s2);
    }
}

__global__ __launch_bounds__(256) void k_scan(const int* __restrict__ deg_col, int* __restrict__ col_off, int* __restrict__ cursor) {
    __shared__ int sd[256];
    int t = threadIdx.x;
    int base_i = t * 32;
    int loc[32];
    int s = 0;
#pragma unroll
    for (int q = 0; q < 32; q++) { loc[q] = deg_col[base_i + q]; s += loc[q]; }
    sd[t] = s;
    __syncthreads();
    for (int d = 1; d < 256; d <<= 1) {
        int v = (t >= d) ? sd[t - d] : 0;
        __syncthreads();
        sd[t] += v;
        __syncthreads();
    }
    int acc = sd[t] - s; // exclusive
#pragma unroll
    for (int q = 0; q < 32; q++) { col_off[base_i + q] = acc; cursor[base_i + q] = acc; acc += loc[q]; }
    if (t == 255) col_off[NN] = acc;
}

// CSR fill; also absorbs former k_loopdinv (deg_row final after k_edge; aeloop for k_gat, dinv for k_regc).
__global__ __launch_bounds__(256) void k_fill(const int* __restrict__ ei, int* __restrict__ cursor,
                                              int* __restrict__ csr_row, int* __restrict__ csr_eid,
                                              const float* __restrict__ sum_ea, const float* __restrict__ M,
                                              float* __restrict__ aeloop, const int* __restrict__ deg_row,
                                              float* __restrict__ dinv) {
    int e = blockIdx.x * 256 + threadIdx.x;
    if (e < 4) {
        float m0 = sum_ea[0] * (1.f / NE), m1 = sum_ea[1] * (1.f / NE), m2 = sum_ea[2] * (1.f / NE);
        aeloop[e] = fmaf(m0, M[0 * 4 + e], fmaf(m1, M[1 * 4 + e], m2 * M[2 * 4 + e]));
    }
    if (e < NN) {
        int d = deg_row[e];
        dinv[e] = d > 0 ? rsqrtf((float)d) : 0.f;
    }
    int r = ei[e], c = ei[NE + e];
    int pos = atomicAdd(&cursor[c], 1);
    csr_row[pos] = r;
    csr_eid[pos] = e;
}

// GAT aggregate + bias + ELU + LayerNorm -> h1 (Half4 wave-wide gathers; R8 structure unchanged)
__global__ __launch_bounds__(256) void k_gat(const int* __restrict__ col_off, const int* __restrict__ csr_row,
                                             const int* __restrict__ csr_eid,
                                             const float* __restrict__ alpha, const float* __restrict__ aeloop,
                                             const float* __restrict__ a_src, const float* __restrict__ a_dst,
                                             const __half* __restrict__ xs, const float* __restrict__ gat_bias,
                                             const float* __restrict__ g, const float* __restrict__ b,
                                             __half* __restrict__ h1) {
    int i = blockIdx.x, t = threadIdx.x, h = t >> 6, lane = t & 63, w = t >> 6;
    int beg = col_off[i], end = col_off[i + 1];
    __shared__ float m_s[4], s_s[4], red[8];
    __shared__ float wl[64][5];       // [edge-in-chunk][head], padded
    __shared__ float accL[4 * 260];   // per-wave partial acc, padded stride 260
    float sl = a_src[i * 4 + h] + a_dst[i * 4 + h] + aeloop[h];
    sl = sl > 0.f ? sl : 0.2f * sl;
    float mx = sl;
    for (int p = beg + lane; p < end; p += 64) mx = fmaxf(mx, alpha[(size_t)csr_eid[p] * 4 + h]);
    mx = wave_max(mx);
    float ss = (lane == 0) ? expf(sl - mx) : 0.f;
    for (int p = beg + lane; p < end; p += 64) ss += expf(alpha[(size_t)csr_eid[p] * 4 + h] - mx);
    ss = wave_sum(ss);
    if (lane == 0) { m_s[h] = mx; s_s[h] = ss; }
    __syncthreads();
    float minv = m_s[h];
    float sinv = 1.f / (s_s[h] + 1e-16f);
    float4 acc = make_float4(0.f, 0.f, 0.f, 0.f);
    int hh = lane >> 4;               // head owning this lane's 4 channels
    for (int cb = beg; cb < end; cb += 64) {
        int ce = min(cb + 64, end);
        int n = ce - cb;
        int p = cb + lane;
        if (p < ce) wl[lane][h] = expf(alpha[(size_t)csr_eid[p] * 4 + h] - minv) * sinv;
        __syncthreads();
        for (int q = w; q < n; q += 4) {
            int r = csr_row[cb + q];
            float wt = wl[q][hh];
            float4 xv = h4tof4(((const Half4*)(xs + (size_t)r * 256))[lane]);
            acc.x = fmaf(wt, xv.x, acc.x);
            acc.y = fmaf(wt, xv.y, acc.y);
            acc.z = fmaf(wt, xv.z, acc.z);
            acc.w = fmaf(wt, xv.w, acc.w);
        }
        __syncthreads();
    }
    ((float4*)(accL + w * 260))[lane] = acc;
    __syncthreads();
    float v = accL[t] + accL[260 + t] + accL[520 + t] + accL[780 + t];
    float wself = expf(sl - minv) * sinv;
    v = fmaf(wself, __half2float(xs[(size_t)i * 256 + t]), v);
    v = eluf(v + gat_bias[t]);
    float s1 = wave_sum(v), s2 = wave_sum(v * v);
    if (lane == 0) { red[w] = s1; red[4 + w] = s2; }
    __syncthreads();
    float mu = (red[0] + red[1] + red[2] + red[3]) * (1.f / 256.f);
    float m2 = (red[4] + red[5] + red[6] + red[7]) * (1.f / 256.f);
    float var = m2 - mu * mu;
    float rs = rsqrtf(var + 1e-5f);
    h1[(size_t)i * 256 + t] = __float2half_rn((v - mu) * rs * g[t] + b[t]);
}

// A = h1 @ W1[:256] + b1 ; B = h1 @ W1[256:]  (tiled ABNT nodes/block; fp16 in/out, f32 math)
__global__ __launch_bounds__(256) void k_AB(const __half* __restrict__ h1, const float* __restrict__ w1,
                                            const float* __restrict__ b1, __half* __restrict__ A, __half* __restrict__ B) {
    __shared__ float hl[ABNT * 256];
    int bk = blockIdx.x, t = threadIdx.x;
    size_t base = (size_t)bk * ABNT;
#pragma unroll
    for (int n = 0; n < ABNT; ++n) hl[n * 256 + t] = __half2float(h1[(base + n) * 256 + t]);
    __syncthreads();
    float accA[ABNT], accB[ABNT];
    float bv = b1[t];
#pragma unroll
    for (int n = 0; n < ABNT; ++n) { accA[n] = bv; accB[n] = 0.f; }
    for (int k = 0; k < 256; ++k) {
        float wa = w1[k * 256 + t];
        float wb = w1[(256 + k) * 256 + t];
#pragma unroll
        for (int n = 0; n < ABNT; ++n) {
            float hv = hl[n * 256 + k];
            accA[n] = fmaf(hv, wa, accA[n]);
            accB[n] = fmaf(hv, wb, accB[n]);
        }
    }
#pragma unroll
    for (int n = 0; n < ABNT; ++n) {
        A[(base + n) * 256 + t] = __float2half_rn(accA[n]);
        B[(base + n) * 256 + t] = __float2half_rn(accB[n]);
    }
}

// regularizer + gcn coefficients: 4 edges per wave via 16-lane groups.
// Each lane issues 8 independent 8B loads (4 A-steps + 4 B-steps) -> 4x memory-level parallelism
// vs the 1-edge-per-wave form; reduce is 4 shfls within the 16-lane group.
__global__ __launch_bounds__(256) void k_regc(const int* __restrict__ ei, const __half* __restrict__ A,
                                              const __half* __restrict__ B, const float* __restrict__ w2,
                                              const float* __restrict__ b2, const float* __restrict__ dinv,
                                              const float* __restrict__ conf1, const float* __restrict__ conf2,
                                              float* __restrict__ adj, float* __restrict__ coef1,
                                              float* __restrict__ coef2) {
    int t = threadIdx.x, w = t >> 6, lane = t & 63;
    int g = lane >> 4, s = lane & 15;
    int e = blockIdx.x * 16 + w * 4 + g;
    int r = ei[e], c = ei[NE + e];
    const Half4* A4 = (const Half4*)(A + (size_t)r * 256);
    const Half4* B4 = (const Half4*)(B + (size_t)c * 256);
    const float4* W4 = (const float4*)w2;
    float sum = 0.f;
#pragma unroll
    for (int st = 0; st < 4; ++st) {
        float4 av = h4tof4(A4[st * 16 + s]);
        float4 bv = h4tof4(B4[st * 16 + s]);
        float4 wv = W4[st * 16 + s];
        float v0 = eluf(av.x + bv.x), v1 = eluf(av.y + bv.y);
        float v2 = eluf(av.z + bv.z), v3 = eluf(av.w + bv.w);
        sum += fmaf(v0, wv.x, fmaf(v1, wv.y, fmaf(v2, wv.z, v3 * wv.w)));
    }
#pragma unroll
    for (int o = 1; o < 16; o <<= 1) sum += __shfl_xor(sum, o);
    if (s == 0) {
        float p = sigmf(sum + b2[0]);
        float adjv;
        if (r != c) { adj[(size_t)r * NN + c] = p; adjv = p; }
        else adjv = 1.f;
        float base = dinv[r] * dinv[c] * 0.5f;
        coef1[e] = base * (conf1[e] + adjv);
        coef2[e] = base * (conf2[e] + adjv);
    }
}

// gcn1: agg = sum coef1*h1[row] (Half4 gathers, wave-per-edge) -> GEMV 256->64 -> ELU -> LN -> h2
__global__ __launch_bounds__(256) void k_gcn1(const int* __restrict__ col_off, const int* __restrict__ csr_row,
                                              const int* __restrict__ csr_eid, const float* __restrict__ coef1,
                                              const __half* __restrict__ h1, const float* __restrict__ W,
                                              const float* __restrict__ bias, const float* __restrict__ g,
                                              const float* __restrict__ bb, float* __restrict__ h2) {
    __shared__ float accL[4 * 260];
    __shared__ float al[256];
    __shared__ float pl[256];
    int i = blockIdx.x, t = threadIdx.x, w = t >> 6, lane = t & 63;
    int beg = col_off[i], end = col_off[i + 1];
    float4 acc = make_float4(0.f, 0.f, 0.f, 0.f);
    for (int p = beg + w; p < end; p += 4) {
        float cf = coef1[csr_eid[p]];
        float4 hv = h4tof4(((const Half4*)(h1 + (size_t)csr_row[p] * 256))[lane]);
        acc.x = fmaf(cf, hv.x, acc.x);
        acc.y = fmaf(cf, hv.y, acc.y);
        acc.z = fmaf(cf, hv.z, acc.z);
        acc.w = fmaf(cf, hv.w, acc.w);
    }
    ((float4*)(accL + w * 260))[lane] = acc;
    __syncthreads();
    al[t] = accL[t] + accL[260 + t] + accL[520 + t] + accL[780 + t];
    __syncthreads();
    int cc = t & 63, q = t >> 6;
    float part = 0.f;
#pragma unroll 4
    for (int k = q * 64; k < q * 64 + 64; k++) part = fmaf(al[k], W[k * 64 + cc], part);
    pl[t] = part;
    __syncthreads();
    if (t < 64) {
        float y = pl[t] + pl[t + 64] + pl[t + 128] + pl[t + 192] + bias[t];
        y = eluf(y);
        float s1 = wave_sum(y), s2 = wave_sum(y * y);
        float mu = s1 * (1.f / 64.f);
        float var = s2 * (1.f / 64.f) - mu * mu;
        h2[(size_t)i * 64 + t] = (y - mu) * rsqrtf(var + 1e-5f) * g[t] + bb[t];
    }
}

// gcn2 + classifier -> logits
__global__ __launch_bounds__(256) void k_gcn2(const int* __restrict__ col_off, const int* __restrict__ csr_row,
                                              const int* __restrict__ csr_eid, const float* __restrict__ coef2,
                                              const float* __restrict__ h2, const float* __restrict__ g2w,
                                              const float* __restrict__ g2b, const float* __restrict__ cw1,
                                              const float* __restrict__ cb1, const float* __restrict__ cw2,
                                              const float* __restrict__ cb2, float* __restrict__ out) {
    __shared__ float zl[4][64];
    __shared__ float ul[4][64];
    __shared__ float tl[4][64];
    int t = threadIdx.x, w = t >> 6, lane = t & 63;
    int i = blockIdx.x * 4 + w;
    int beg = col_off[i], end = col_off[i + 1];
    float z = 0.f;
    for (int p = beg; p < end; ++p)
        z = fmaf(coef2[csr_eid[p]], h2[(size_t)csr_row[p] * 64 + lane], z);
    zl[w][lane] = z;
    __syncthreads();
    float u = g2b[lane];
#pragma unroll 4
    for (int k = 0; k < 64; k++) u = fmaf(zl[w][k], g2w[k * 64 + lane], u);
    ul[w][lane] = u;
    __syncthreads();
    float t1 = cb1[lane];
#pragma unroll 4
    for (int k = 0; k < 64; k++) t1 = fmaf(ul[w][k], cw1[k * 64 + lane], t1);
    t1 = eluf(t1);
    tl[w][lane] = t1;
    __syncthreads();
    if (lane < 8) {
        float o = cb2[lane];
#pragma unroll 4
        for (int k = 0; k < 64; k++) o = fmaf(tl[w][k], cw2[k * 8 + lane], o);
        out[(size_t)i * 8 + lane] = o;
    }
}

// ---------------- launch ----------------
extern "C" void kernel_launch(void* const* d_in, const int* in_sizes, int n_in,
                              void* d_out, int out_size, void* d_ws, size_t ws_size,
                              hipStream_t stream) {
    const float* x           = (const float*)d_in[0];
    const float* edge_attr   = (const float*)d_in[1];
    const float* gat_lin_w   = (const float*)d_in[2];
    const float* gat_lin_edge_w = (const float*)d_in[3];
    const float* att_src     = (const float*)d_in[4];
    const float* att_dst     = (const float*)d_in[5];
    const float* att_edge    = (const float*)d_in[6];
    const float* gat_bias    = (const float*)d_in[7];
    const float* norm1_g     = (const float*)d_in[8];
    const float* norm1_b     = (const float*)d_in[9];
    const float* reg_w1      = (const float*)d_in[10];
    const float* reg_b1      = (const float*)d_in[11];
    const float* reg_w2      = (const float*)d_in[12];
    const float* reg_b2      = (const float*)d_in[13];
    const float* g1_lin_w    = (const float*)d_in[14];
    const float* g1_lin_b    = (const float*)d_in[15];
    const float* g1_conf_w   = (const float*)d_in[16];
    const float* g1_conf_b   = (const float*)d_in[17];
    const float* norm2_g     = (const float*)d_in[18];
    const float* norm2_b     = (const float*)d_in[19];
    const float* g2_lin_w    = (const float*)d_in[20];
    const float* g2_lin_b    = (const float*)d_in[21];
    const float* g2_conf_w   = (const float*)d_in[22];
    const float* g2_conf_b   = (const float*)d_in[23];
    const float* cls_w1      = (const float*)d_in[24];
    const float* cls_b1      = (const float*)d_in[25];
    const float* cls_w2      = (const float*)d_in[26];
    const float* cls_b2      = (const float*)d_in[27];
    const int*   edge_index  = (const int*)d_in[28];

    float* out = (float*)d_out;
    float* adj = out + (size_t)NN * NCLS;

    float* wsf   = (float*)d_ws;
    __half* xs   = (__half*)(wsf + OFF_XS);
    float* a_src = wsf + OFF_ASRC;
    float* a_dst = wsf + OFF_ADST;
    float* alpha = wsf + OFF_ALPHA;
    float* conf1 = wsf + OFF_CONF1;
    float* conf2 = wsf + OFF_CONF2;
    float* coef1 = wsf + OFF_COEF1;
    float* coef2 = wsf + OFF_COEF2;
    __half* h1   = (__half*)(wsf + OFF_H1);
    __half* A    = (__half*)(wsf + OFF_A);
    __half* B    = (__half*)(wsf + OFF_B);
    float* h2    = wsf + OFF_H2;
    float* dinv  = wsf + OFF_DINV;
    float* sum_ea= wsf + OFF_SUMEA;
    float* M     = wsf + OFF_M;
    float* aeloop= wsf + OFF_AELOOP;
    int* ib      = (int*)(wsf + OFF_INT);
    int* deg_col = ib + IOFF_DEGC;
    int* deg_row = ib + IOFF_DEGR;
    int* col_off = ib + IOFF_COLOFF;
    int* cursor  = ib + IOFF_CURSOR;
    int* csr_row = ib + IOFF_CSRROW;
    int* csr_eid = ib + IOFF_CSREID;

    // 1. zero adj (268 MB) via fill engine
    hipMemsetAsync(adj, 0, (size_t)NN * NN * sizeof(float), stream);
    // 2. node transform (+ counter zeroing, M precompute)
    k_node<<<NN / NDNT, 256, 0, stream>>>(x, gat_lin_w, att_src, att_dst,
                                          gat_lin_edge_w, att_edge,
                                          xs, a_src, a_dst, deg_col, deg_row, sum_ea, M);
    // 3. per-edge logits/conf/degrees (+ adj diag, after memset in stream order)
    k_edge<<<NE / 256, 256, 0, stream>>>(edge_index, edge_attr, M, a_src, a_dst,
                                         g1_conf_w, g1_conf_b, g2_conf_w, g2_conf_b,
                                         alpha, conf1, conf2, deg_col, deg_row, sum_ea, adj);
    // 4. CSR scan
    k_scan<<<1, 256, 0, stream>>>(deg_col, col_off, cursor);
    // 5. CSR fill (+ aeloop, dinv)
    k_fill<<<NE / 256, 256, 0, stream>>>(edge_index, cursor, csr_row, csr_eid,
                                         sum_ea, M, aeloop, deg_row, dinv);
    // 6. GAT aggregate + ELU + LN -> h1
    k_gat<<<NN, 256, 0, stream>>>(col_off, csr_row, csr_eid, alpha, aeloop, a_src, a_dst,
                                  xs, gat_bias, norm1_g, norm1_b, h1);
    // 7. regularizer factored GEMMs
    k_AB<<<NN / ABNT, 256, 0, stream>>>(h1, reg_w1, reg_b1, A, B);
    // 8. per-edge prob + adj scatter + gcn coefficients (4 edges/wave, 16-lane groups)
    k_regc<<<NE / 16, 256, 0, stream>>>(edge_index, A, B, reg_w2, reg_b2, dinv,
                                        conf1, conf2, adj, coef1, coef2);
    // 9. gcn1 -> h2
    k_gcn1<<<NN, 256, 0, stream>>>(col_off, csr_row, csr_eid, coef1, h1,
                                   g1_lin_w, g1_lin_b, norm2_g, norm2_b, h2);
    // 10. gcn2 + classifier -> logits
    k_gcn2<<<NN / 4, 256, 0, stream>>>(col_off, csr_row, csr_eid, coef2, h2,
                                       g2_lin_w, g2_lin_b, cls_w1, cls_b1, cls_w2, cls_b2, out);
    (void)in_sizes; (void)n_in; (void)out_size; (void)ws_size;
}